// Round 3
// baseline (423.849 us; speedup 1.0000x reference)
//
#include <hip/hip_runtime.h>
#include <cstdint>
#include <cstddef>

#define NN 4096
#define DD 128

using short8 = __attribute__((ext_vector_type(8))) short;
using f32x4  = __attribute__((ext_vector_type(4))) float;
typedef unsigned long long u64;

typedef __attribute__((address_space(1))) void gvoid;
typedef __attribute__((address_space(3))) void lvoid;

__device__ __forceinline__ void async16(const void* g, void* l) {
  __builtin_amdgcn_global_load_lds((gvoid*)g, (lvoid*)l, 16, 0, 0);
}

__device__ __forceinline__ float dec_f(const void* p) {
  if (!p) return 1.0f;
  int b = *(const int*)p;
  return (b >= 0 && b < 1000000) ? (float)b : __int_as_float(b);
}
__device__ __forceinline__ int dec_i(const void* p) {
  if (!p) return 4;
  int b = *(const int*)p;
  return (b >= 0 && b < 1000000) ? b : (int)__int_as_float(b);
}

__device__ __forceinline__ unsigned short f2bf(float f) {
  union { float f; unsigned int u; } v; v.f = f;
  unsigned int u = v.u;
  unsigned int r = (u + 0x7fffu + ((u >> 16) & 1u)) >> 16;
  return (unsigned short)r;
}

// sorted-4 insert of packed key (d2_bits<<32 | idx), ascending (exact)
__device__ __forceinline__ void ins4(u64 (&l)[4], u64 k) {
#pragma unroll
  for (int t = 0; t < 4; ++t) {
    u64 old = l[t];
    bool bt = k < old;
    l[t] = bt ? k : old;
    k = bt ? old : k;
  }
}

// stage ROWS x KC bf16 tile (16B chunks; physical chunk p holds logical p^(r&7))
template <int ROWS, int KC, int NTHR>
__device__ __forceinline__ void stage2(const unsigned short* src, int row0, int kb,
                                       unsigned short* dst, int tid, int stride) {
  const int CPR = KC / 8;
  const int ITER = (ROWS * CPR) / NTHR;
#pragma unroll
  for (int t = 0; t < ITER; ++t) {
    int id = tid + t * NTHR;
    int r = id / CPR;
    int p = id % CPR;
    int lc = p ^ (r & 7);
    const void* g = src + (size_t)(row0 + r) * stride + kb + lc * 8;
    async16(g, dst + (size_t)(id & ~63) * 8);
  }
}

template <int CPR>
__device__ __forceinline__ short8 fragN(const unsigned short* t, int row, int ch) {
  return *(const short8*)(t + (size_t)(row * CPR + (ch ^ (row & 7))) * 8);
}

// ---------------- K1: rowsum(A), d = rsqrt, A -> bf16, zero split-K counters ----------------
__global__ __launch_bounds__(256) void k_rowsum_scale(
    const float* __restrict__ A, float* __restrict__ rowsumA,
    float* __restrict__ dvec, unsigned short* __restrict__ Ah,
    int* __restrict__ cnt) {
  int row = blockIdx.x;
  int tid = threadIdx.x;
  if (row == 0 && tid < 128) cnt[tid] = 0;   // cnt1 (pass1) + cnt2 (pass2)
  const float4* Arow = (const float4*)(A + (size_t)row * NN);
  float s = 0.f;
#pragma unroll
  for (int l = 0; l < 4; ++l) {
    int idx = tid + l * 256;
    float4 v = Arow[idx];
    s += (v.x + v.y) + (v.z + v.w);
    ushort4 h = {f2bf(v.x), f2bf(v.y), f2bf(v.z), f2bf(v.w)};
    *(ushort4*)(Ah + (size_t)row * NN + idx * 4) = h;
  }
  __shared__ float red[256];
  red[tid] = s;
  __syncthreads();
  if (tid < 64) {
    s = red[tid] + red[tid + 64] + red[tid + 128] + red[tid + 192];
#pragma unroll
    for (int off = 32; off > 0; off >>= 1) s += __shfl_down(s, off, 64);
    if (tid == 0) { rowsumA[row] = s; dvec[row] = rsqrtf(s); }
  }
}

// ---- K2: fused  U = (scale .* x) @ W ; emit U fp32 (opt) + UTh bf16 transposed ----
__global__ __launch_bounds__(256) void k_xwt(
    const float* __restrict__ x, const float* __restrict__ scale,
    const float* __restrict__ W, float* __restrict__ U,
    unsigned short* __restrict__ UTh) {
  int r0 = blockIdx.x * 16, tid = threadIdx.x;
  int tr = tid >> 4, tc = tid & 15;
  __shared__ float Xs[16 * 132];
  __shared__ float Ws[32 * 128];
  __shared__ unsigned short Ts[128 * 16];
  __shared__ float ssc[16];
  if (tid < 16) ssc[tid] = scale[r0 + tid];
  __syncthreads();
#pragma unroll
  for (int l = 0; l < 2; ++l) {
    int idx = tid + l * 256;
    int r = idx >> 5, c4 = (idx & 31) << 2;
    float4 xv = *(const float4*)(x + (size_t)(r0 + r) * DD + c4);
    float sc = ssc[r];
    float4 o = {sc * xv.x, sc * xv.y, sc * xv.z, sc * xv.w};
    *(float4*)(Xs + r * 132 + c4) = o;
  }
  float acc[8];
#pragma unroll
  for (int u = 0; u < 8; ++u) acc[u] = 0.f;
  for (int t0 = 0; t0 < 128; t0 += 32) {
    __syncthreads();
#pragma unroll
    for (int l = 0; l < 4; ++l) {
      int idx = tid + l * 256;
      int tt = idx >> 5, c4 = (idx & 31) << 2;
      *(float4*)(Ws + tt * 128 + c4) = *(const float4*)(W + (size_t)(t0 + tt) * DD + c4);
    }
    __syncthreads();
#pragma unroll 8
    for (int tt = 0; tt < 32; ++tt) {
      float g = Xs[tr * 132 + t0 + tt];
      float4 w0 = *(const float4*)(Ws + tt * 128 + tc * 8);
      float4 w1 = *(const float4*)(Ws + tt * 128 + tc * 8 + 4);
      acc[0] = fmaf(g, w0.x, acc[0]); acc[1] = fmaf(g, w0.y, acc[1]);
      acc[2] = fmaf(g, w0.z, acc[2]); acc[3] = fmaf(g, w0.w, acc[3]);
      acc[4] = fmaf(g, w1.x, acc[4]); acc[5] = fmaf(g, w1.y, acc[5]);
      acc[6] = fmaf(g, w1.z, acc[6]); acc[7] = fmaf(g, w1.w, acc[7]);
    }
  }
  if (U) {
    size_t off = (size_t)(r0 + tr) * DD + tc * 8;
    float4 o0 = {acc[0], acc[1], acc[2], acc[3]};
    float4 o1 = {acc[4], acc[5], acc[6], acc[7]};
    *(float4*)(U + off) = o0;
    *(float4*)(U + off + 4) = o1;
  }
#pragma unroll
  for (int j = 0; j < 8; ++j) Ts[(tc * 8 + j) * 16 + tr] = f2bf(acc[j]);
  __syncthreads();
  {
    int row = tid >> 1, h = tid & 1;
    *(short8*)(UTh + (size_t)row * NN + r0 + h * 8) = *(const short8*)(Ts + row * 16 + h * 8);
  }
}

// ---- K2b: fused merge(pkey,u64 exact) -> S/d2 + U2 = (d2 .* x) @ W2 ----
__global__ __launch_bounds__(256) void k_mxwt(
    const u64* __restrict__ pkey, const float* __restrict__ rowsumA,
    const float* __restrict__ x, const float* __restrict__ W,
    float* __restrict__ sval, int* __restrict__ sidx, float* __restrict__ d2vec,
    float* __restrict__ U, unsigned short* __restrict__ UTh,
    const void* kptr, const void* sigptr) {
  int r0 = blockIdx.x * 16, tid = threadIdx.x;
  int tr = tid >> 4, tc = tid & 15;
  __shared__ float Xs[16 * 132];
  __shared__ float Ws[32 * 128];
  __shared__ unsigned short Ts[128 * 16];
  __shared__ u64 mk[256][4];
  __shared__ float ds[16];

  // parallel 16-way merge: thread (r,p) owns one partial sorted list
  {
    int r = tid >> 4, p = tid & 15;
    const u64* src = pkey + ((size_t)(r0 + r) * 16 + p) * 4;
    ulonglong2 k0 = *(const ulonglong2*)src;
    ulonglong2 k1 = *(const ulonglong2*)(src + 2);
    mk[tid][0] = k0.x; mk[tid][1] = k0.y; mk[tid][2] = k1.x; mk[tid][3] = k1.y;
  }
  __syncthreads();
#pragma unroll
  for (int s = 8; s > 0; s >>= 1) {
    int p = tid & 15;
    if (p < s) {
      u64 b[4] = {mk[tid][0], mk[tid][1], mk[tid][2], mk[tid][3]};
#pragma unroll
      for (int q = 0; q < 4; ++q) ins4(b, mk[tid + s][q]);
      mk[tid][0] = b[0]; mk[tid][1] = b[1]; mk[tid][2] = b[2]; mk[tid][3] = b[3];
    }
    __syncthreads();
  }
  if ((tid & 15) == 0) {
    int rl = tid >> 4;
    int r = r0 + rl;
    int kk = dec_i(kptr); kk = kk < 1 ? 1 : (kk > 4 ? 4 : kk);
    float inv2s = 0.5f / dec_f(sigptr);
    float srw = 0.f;
#pragma unroll
    for (int s = 0; s < 4; ++s) {
      if (s < kk) {
        u64 key = mk[tid][s];
        float d2 = __uint_as_float((unsigned)(key >> 32));
        float S = __expf(-sqrtf(d2 + 1e-10f) * inv2s);
        sval[r * 8 + s] = S;
        sidx[r * 8 + s] = (int)(key & 0xffffffffu);
        srw += S;
      }
    }
    float dd = rsqrtf(rowsumA[r] + srw);
    d2vec[r] = dd;
    ds[rl] = dd;
  }
  __syncthreads();

#pragma unroll
  for (int l = 0; l < 2; ++l) {
    int idx = tid + l * 256;
    int r = idx >> 5, c4 = (idx & 31) << 2;
    float4 xv = *(const float4*)(x + (size_t)(r0 + r) * DD + c4);
    float sc = ds[r];
    float4 o = {sc * xv.x, sc * xv.y, sc * xv.z, sc * xv.w};
    *(float4*)(Xs + r * 132 + c4) = o;
  }
  float acc[8];
#pragma unroll
  for (int u = 0; u < 8; ++u) acc[u] = 0.f;
  for (int t0 = 0; t0 < 128; t0 += 32) {
    __syncthreads();
#pragma unroll
    for (int l = 0; l < 4; ++l) {
      int idx = tid + l * 256;
      int tt = idx >> 5, c4 = (idx & 31) << 2;
      *(float4*)(Ws + tt * 128 + c4) = *(const float4*)(W + (size_t)(t0 + tt) * DD + c4);
    }
    __syncthreads();
#pragma unroll 8
    for (int tt = 0; tt < 32; ++tt) {
      float g = Xs[tr * 132 + t0 + tt];
      float4 w0 = *(const float4*)(Ws + tt * 128 + tc * 8);
      float4 w1 = *(const float4*)(Ws + tt * 128 + tc * 8 + 4);
      acc[0] = fmaf(g, w0.x, acc[0]); acc[1] = fmaf(g, w0.y, acc[1]);
      acc[2] = fmaf(g, w0.z, acc[2]); acc[3] = fmaf(g, w0.w, acc[3]);
      acc[4] = fmaf(g, w1.x, acc[4]); acc[5] = fmaf(g, w1.y, acc[5]);
      acc[6] = fmaf(g, w1.z, acc[6]); acc[7] = fmaf(g, w1.w, acc[7]);
    }
  }
  {
    size_t off = (size_t)(r0 + tr) * DD + tc * 8;
    float4 o0 = {acc[0], acc[1], acc[2], acc[3]};
    float4 o1 = {acc[4], acc[5], acc[6], acc[7]};
    *(float4*)(U + off) = o0;
    *(float4*)(U + off + 4) = o1;
  }
#pragma unroll
  for (int j = 0; j < 8; ++j) Ts[(tc * 8 + j) * 16 + tr] = f2bf(acc[j]);
  __syncthreads();
  {
    int row = tid >> 1, h = tid & 1;
    *(short8*)(UTh + (size_t)row * NN + r0 + h * 8) = *(const short8*)(Ts + row * 16 + h * 8);
  }
}

// ---- K4: MFMA bf16 GEMM split-K + fused last-block reduction/epilogue ----
// grid: 32 m-tiles x SPLIT; last block per m-tile reduces all partials (p-order
// identical to the old k_red -> bit-identical results).
template <int SPLIT>
__global__ __launch_bounds__(256) void k_gemm_fused(
    const unsigned short* __restrict__ Ah, const unsigned short* __restrict__ Bh,
    float* __restrict__ G, int* __restrict__ cnt,
    const float* __restrict__ dvec, const float* __restrict__ bvec, int leaky,
    float* __restrict__ Out, unsigned short* __restrict__ zh,
    float* __restrict__ sqout,
    const float* __restrict__ Usp, const float* __restrict__ sval,
    const int* __restrict__ sidx, const void* kptr) {
  __shared__ __align__(16) unsigned short As_h[128 * 64];
  __shared__ __align__(16) unsigned short Bs_h[128 * 64];
  __shared__ float redsh[256];
  __shared__ int islast;

  int bx = blockIdx.x;
  int mt = bx / SPLIT, sp = bx % SPLIT;
  int m0 = mt * 128;
  const int KLEN = NN / SPLIT;
  int ks = sp * KLEN;
  int tid = threadIdx.x, lane = tid & 63, w = tid >> 6;
  int wm = w >> 1, wn = w & 1;
  int l15 = lane & 15, quad = lane >> 4;

  f32x4 acc[4][4];
#pragma unroll
  for (int a = 0; a < 4; ++a)
#pragma unroll
    for (int b = 0; b < 4; ++b) acc[a][b] = (f32x4){0.f, 0.f, 0.f, 0.f};

  for (int kt = 0; kt < KLEN; kt += 64) {
    int kb = ks + kt;
    __syncthreads();
    stage2<128, 64, 256>(Ah, m0, kb, As_h, tid, NN);
    stage2<128, 64, 256>(Bh, 0, kb, Bs_h, tid, NN);
    __syncthreads();
#pragma unroll
    for (int k0 = 0; k0 < 64; k0 += 32) {
      int ch = (k0 >> 3) + quad;
      short8 a_h[4], b_h[4];
#pragma unroll
      for (int f = 0; f < 4; ++f) {
        a_h[f] = fragN<8>(As_h, wm * 64 + f * 16 + l15, ch);
        b_h[f] = fragN<8>(Bs_h, wn * 64 + f * 16 + l15, ch);
      }
#pragma unroll
      for (int fm = 0; fm < 4; ++fm)
#pragma unroll
        for (int fn = 0; fn < 4; ++fn)
          acc[fm][fn] = __builtin_amdgcn_mfma_f32_16x16x32_bf16(a_h[fm], b_h[fn], acc[fm][fn], 0, 0, 0);
    }
  }
  {
    float* Gp = G + (size_t)sp * NN * DD;
#pragma unroll
    for (int fm = 0; fm < 4; ++fm) {
      int rb = m0 + wm * 64 + fm * 16 + quad * 4;
#pragma unroll
      for (int fn = 0; fn < 4; ++fn) {
        int c = wn * 64 + fn * 16 + l15;
#pragma unroll
        for (int i = 0; i < 4; ++i)
          Gp[(size_t)(rb + i) * DD + c] = acc[fm][fn][i];
      }
    }
  }

  // ---- arrival: release stores, last block reduces ----
  __threadfence();                       // release: G stores visible before count
  __syncthreads();                       // all threads fenced
  if (tid == 0) islast = (atomicAdd(&cnt[mt], 1) == SPLIT - 1);
  __syncthreads();
  if (!islast) return;
  __threadfence();                       // acquire: see remote G partials

  int kk = 0;
  if (sidx != nullptr) { kk = dec_i(kptr); kk = kk < 1 ? 1 : (kk > 4 ? 4 : kk); }
  int tr = tid >> 4, tc = tid & 15;
#pragma unroll 1
  for (int sub = 0; sub < 8; ++sub) {
    int r = m0 + sub * 16 + tr;
    size_t off = (size_t)r * DD + tc * 8;
    float acc2[8];
#pragma unroll
    for (int u = 0; u < 8; ++u) acc2[u] = 0.f;
#pragma unroll
    for (int p = 0; p < SPLIT; ++p) {
      const float* gp = G + (size_t)p * NN * DD + off;
      float4 g0 = *(const float4*)gp;
      float4 g1 = *(const float4*)(gp + 4);
      acc2[0] += g0.x; acc2[1] += g0.y; acc2[2] += g0.z; acc2[3] += g0.w;
      acc2[4] += g1.x; acc2[5] += g1.y; acc2[6] += g1.z; acc2[7] += g1.w;
    }
    if (sidx != nullptr) {
      for (int t = 0; t < kk; ++t) {
        float sv = sval[r * 8 + t];
        int id = sidx[r * 8 + t];
        const float* vr = Usp + (size_t)id * DD + tc * 8;
        float4 w0 = *(const float4*)vr;
        float4 w1 = *(const float4*)(vr + 4);
        acc2[0] = fmaf(sv, w0.x, acc2[0]); acc2[1] = fmaf(sv, w0.y, acc2[1]);
        acc2[2] = fmaf(sv, w0.z, acc2[2]); acc2[3] = fmaf(sv, w0.w, acc2[3]);
        acc2[4] = fmaf(sv, w1.x, acc2[4]); acc2[5] = fmaf(sv, w1.y, acc2[5]);
        acc2[6] = fmaf(sv, w1.z, acc2[6]); acc2[7] = fmaf(sv, w1.w, acc2[7]);
      }
    }
    float d = dvec[r];
    float4 b0 = *(const float4*)(bvec + tc * 8);
    float4 b1 = *(const float4*)(bvec + tc * 8 + 4);
    float bb[8] = {b0.x, b0.y, b0.z, b0.w, b1.x, b1.y, b1.z, b1.w};
    float o[8];
#pragma unroll
    for (int u = 0; u < 8; ++u) {
      float v = fmaf(d, acc2[u], bb[u]);
      if (leaky) v = v > 0.f ? v : 0.1f * v;
      o[u] = v;
    }
    if (Out) {
      float4 o0 = {o[0], o[1], o[2], o[3]};
      float4 o1 = {o[4], o[5], o[6], o[7]};
      *(float4*)(Out + off) = o0;
      *(float4*)(Out + off + 4) = o1;
    }
    if (zh) {
      ushort4 h0 = {f2bf(o[0]), f2bf(o[1]), f2bf(o[2]), f2bf(o[3])};
      ushort4 h1 = {f2bf(o[4]), f2bf(o[5]), f2bf(o[6]), f2bf(o[7])};
      *(ushort4*)(zh + off) = h0;
      *(ushort4*)(zh + off + 4) = h1;
    }
    if (sqout != nullptr) {
      float p = 0.f;
#pragma unroll
      for (int u = 0; u < 8; ++u) p = fmaf(o[u], o[u], p);
      redsh[tid] = p;
      __syncthreads();
      if (tc == 0) {
        float s = 0.f;
#pragma unroll
        for (int i = 0; i < 16; ++i) s += redsh[tr * 16 + i];
        sqout[r] = s;
      }
      __syncthreads();
    }
  }
}

// ---- K6: MFMA bf16 Z@Z^T, fused d2-key top-4 per (row, j-slice), u64 exact keys ----
// grid 1024: mt (64 m-tiles of 64) x jp (16 j-slices of 256); block 512 (8 waves)
__global__ __launch_bounds__(512, 8) void k_scores(
    const unsigned short* __restrict__ Zh,
    const float* __restrict__ sq, u64* __restrict__ pkey) {
  __shared__ __align__(16) unsigned short Am[64 * 128];   // 16 KB; merge lists alias
  __shared__ __align__(16) unsigned short Bj[64 * 128];   // 16 KB; Stile aliases
  float* Stile = (float*)&Bj[0];          // [64][64], XOR-swizzled float4 slots
  u64* mv = (u64*)&Am[0];                 // [512][4] packed keys (16 KB)

  int bx = blockIdx.x;
  int mt = bx >> 4, jp = bx & 15;
  int m0 = mt * 64, j0 = jp * 256;
  int tid = threadIdx.x, lane = tid & 63, w = tid >> 6;
  int wm = w >> 2, wn = w & 3;            // wave tile: 32 rows x 16 cols
  int l15 = lane & 15, quad = lane >> 4;

  stage2<64, 128, 512>(Zh, m0, 0, Am, tid, DD);

  int srow = tid >> 3;         // scan row 0..63
  int sc = tid & 7;            // scan col-octet
  float sqi_r = sq[m0 + srow];

  u64 lst[4];
#pragma unroll
  for (int s = 0; s < 4; ++s) lst[s] = ~0ull;
  unsigned cutb = 0xffffffffu;            // hi32 of lst[3]

  for (int jt = 0; jt < 4; ++jt) {
    int jrow0 = j0 + jt * 64;
    __syncthreads();           // prev scan done (Stile = Bj about to be restaged)
    stage2<64, 128, 512>(Zh, jrow0, 0, Bj, tid, DD);
    __syncthreads();           // DMA visible (covers A on first iter)

    f32x4 acc[2];
    acc[0] = (f32x4){0.f, 0.f, 0.f, 0.f};
    acc[1] = (f32x4){0.f, 0.f, 0.f, 0.f};
#pragma unroll
    for (int kc = 0; kc < 4; ++kc) {
      int ch = kc * 4 + quad;
      short8 ah0 = fragN<16>(Am, wm * 32 + l15, ch);
      short8 ah1 = fragN<16>(Am, wm * 32 + 16 + l15, ch);
      short8 bh  = fragN<16>(Bj, wn * 16 + l15, ch);
      acc[0] = __builtin_amdgcn_mfma_f32_16x16x32_bf16(ah0, bh, acc[0], 0, 0, 0);
      acc[1] = __builtin_amdgcn_mfma_f32_16x16x32_bf16(ah1, bh, acc[1], 0, 0, 0);
    }
    __syncthreads();           // all Bj/Am frag reads done before Stile clobbers Bj

    // epilogue: Stile[r][c] = sqj - 2*dot, swizzled slot = (c>>2)^(r&7)
    {
      int c = wn * 16 + l15;
      float sqjv = sq[jrow0 + c];
      int cslot = c >> 2, cw = c & 3;
#pragma unroll
      for (int fm = 0; fm < 2; ++fm) {
        int rb = wm * 32 + fm * 16 + quad * 4;
#pragma unroll
        for (int i = 0; i < 4; ++i) {
          int r = rb + i;
          Stile[r * 64 + ((cslot ^ (r & 7)) << 2) + cw] = fmaf(-2.f, acc[fm][i], sqjv);
        }
      }
    }
    __syncthreads();           // Stile visible

    // scan: 8 threads/row, 8 cands each (2 swizzled float4 reads)
    // exact early-exit: packed > lst[3] is a no-op; v>=0 so bit order = float
    // order, thus skip iff float_bits(v) > hi32(lst[3]).
#pragma unroll
    for (int q = 0; q < 2; ++q) {
      int slot = sc * 2 + q;
      float4 kv = *(const float4*)(Stile + srow * 64 + ((slot ^ (srow & 7)) << 2));
      int jb = jrow0 + sc * 8 + q * 4;
      float ke[4] = {kv.x, kv.y, kv.z, kv.w};
#pragma unroll
      for (int e = 0; e < 4; ++e) {
        float v = fmaxf(sqi_r + ke[e], 0.f);
        unsigned vb = __float_as_uint(v);
        if (vb <= cutb) {
          ins4(lst, ((u64)vb << 32) | (unsigned)(jb + e));
          cutb = (unsigned)(lst[3] >> 32);
        }
      }
    }
  }

  __syncthreads();             // last scan + last Am frag reads done
#pragma unroll
  for (int s = 0; s < 4; ++s) mv[tid * 4 + s] = lst[s];
  __syncthreads();
  if (tid < 64) {
    u64 best[4] = {~0ull, ~0ull, ~0ull, ~0ull};
    for (int g = 0; g < 8; ++g) {
      int src = tid * 8 + g;
#pragma unroll
      for (int s = 0; s < 4; ++s) ins4(best, mv[src * 4 + s]);
    }
#pragma unroll
    for (int s = 0; s < 4; ++s)
      pkey[((size_t)(m0 + tid) * 16 + jp) * 4 + s] = best[s];
  }
}

extern "C" void kernel_launch(void* const* d_in, const int* in_sizes, int n_in,
                              void* d_out, int out_size, void* d_ws, size_t ws_size,
                              hipStream_t stream) {
  const float* x  = (const float*)d_in[0];
  const float* A  = (const float*)d_in[1];
  const float* W1 = (const float*)d_in[2];
  const float* b1 = (const float*)d_in[3];
  const float* W2 = (const float*)d_in[4];
  const float* b2 = (const float*)d_in[5];
  const void* sig = (n_in > 6) ? d_in[6] : nullptr;
  const void* kp  = (n_in > 7) ? d_in[7] : nullptr;

  float* ws = (float*)d_ws;
  float* rowsumA = ws;                                   // 4096
  float* dvec    = ws + 4096;                            // 4096
  float* d2vec   = ws + 8192;                            // 4096
  float* sqv     = ws + 12288;                           // 4096
  int*   cnt     = (int*)(ws + 16384);                   // 128 ints (pass1 | pass2)
  float* sval    = ws + 16512;                           // 32768
  int*   sidx    = (int*)(ws + 49280);                   // 32768
  u64*   pkey    = (u64*)(ws + 82048);                   // 262144 u64 = 524288 floats
  unsigned short* Zh  = (unsigned short*)(ws + 606336);  // 524288 u16 = 262144 floats
  float* U       = ws + 868480;                          // 524288 f32
  unsigned short* UTh = (unsigned short*)(ws + 1392768); // 524288 u16 = 262144 floats
  unsigned short* Ah  = (unsigned short*)(ws + 1654912); // 16777216 u16 = 8388608 floats
  float* G       = ws + 10043520;                        // SPLIT * 524288 f32

  const size_t F16 = 10043520 + 16 * 524288;  // floats (~73.7 MB)
  int split16 = (ws_size >= F16 * 4);

  k_rowsum_scale<<<4096, 256, 0, stream>>>(A, rowsumA, dvec, Ah, cnt);
  // pass 1: Z = leaky(d * (A @ ((d.*x)@W1)) + b1), emit Zh + sq
  k_xwt<<<256, 256, 0, stream>>>(x, dvec, W1, nullptr, UTh);
  if (split16) {
    k_gemm_fused<16><<<512, 256, 0, stream>>>(Ah, UTh, G, cnt, dvec, b1, 1,
                                              nullptr, Zh, sqv,
                                              nullptr, nullptr, nullptr, nullptr);
  } else {
    k_gemm_fused<4><<<128, 256, 0, stream>>>(Ah, UTh, G, cnt, dvec, b1, 1,
                                             nullptr, Zh, sqv,
                                             nullptr, nullptr, nullptr, nullptr);
  }
  // scores + top-k
  k_scores<<<1024, 512, 0, stream>>>(Zh, sqv, pkey);
  // fused merge + pass-2 feature transform
  k_mxwt<<<256, 256, 0, stream>>>(pkey, rowsumA, x, W2, sval, sidx, d2vec,
                                  U, UTh, kp, sig);
  // pass 2: out = d2 * (A @ ((d2.*x)@W2) + sparse) + b2
  if (split16) {
    k_gemm_fused<16><<<512, 256, 0, stream>>>(Ah, UTh, G, cnt + 64, d2vec, b2, 0,
                                              (float*)d_out, nullptr, nullptr,
                                              U, sval, sidx, kp);
  } else {
    k_gemm_fused<4><<<128, 256, 0, stream>>>(Ah, UTh, G, cnt + 64, d2vec, b2, 0,
                                             (float*)d_out, nullptr, nullptr,
                                             U, sval, sidx, kp);
  }
}

// Round 4
// 207.299 us; speedup vs baseline: 2.0446x; 2.0446x over previous
//
#include <hip/hip_runtime.h>
#include <cstdint>
#include <cstddef>

#define NN 4096
#define DD 128

using short8 = __attribute__((ext_vector_type(8))) short;
using f32x4  = __attribute__((ext_vector_type(4))) float;
typedef unsigned long long u64;

typedef __attribute__((address_space(1))) void gvoid;
typedef __attribute__((address_space(3))) void lvoid;

__device__ __forceinline__ void async16(const void* g, void* l) {
  __builtin_amdgcn_global_load_lds((gvoid*)g, (lvoid*)l, 16, 0, 0);
}

__device__ __forceinline__ float dec_f(const void* p) {
  if (!p) return 1.0f;
  int b = *(const int*)p;
  return (b >= 0 && b < 1000000) ? (float)b : __int_as_float(b);
}
__device__ __forceinline__ int dec_i(const void* p) {
  if (!p) return 4;
  int b = *(const int*)p;
  return (b >= 0 && b < 1000000) ? b : (int)__int_as_float(b);
}

__device__ __forceinline__ unsigned short f2bf(float f) {
  union { float f; unsigned int u; } v; v.f = f;
  unsigned int u = v.u;
  unsigned int r = (u + 0x7fffu + ((u >> 16) & 1u)) >> 16;
  return (unsigned short)r;
}

// sorted-4 insert of packed key (d2_bits<<32 | idx), ascending (exact)
__device__ __forceinline__ void ins4(u64 (&l)[4], u64 k) {
#pragma unroll
  for (int t = 0; t < 4; ++t) {
    u64 old = l[t];
    bool bt = k < old;
    l[t] = bt ? k : old;
    k = bt ? old : k;
  }
}

// stage ROWS x KC bf16 tile (16B chunks; physical chunk p holds logical p^(r&7))
template <int ROWS, int KC, int NTHR>
__device__ __forceinline__ void stage2(const unsigned short* src, int row0, int kb,
                                       unsigned short* dst, int tid, int stride) {
  const int CPR = KC / 8;
  const int ITER = (ROWS * CPR) / NTHR;
#pragma unroll
  for (int t = 0; t < ITER; ++t) {
    int id = tid + t * NTHR;
    int r = id / CPR;
    int p = id % CPR;
    int lc = p ^ (r & 7);
    const void* g = src + (size_t)(row0 + r) * stride + kb + lc * 8;
    async16(g, dst + (size_t)(id & ~63) * 8);
  }
}

template <int CPR>
__device__ __forceinline__ short8 fragN(const unsigned short* t, int row, int ch) {
  return *(const short8*)(t + (size_t)(row * CPR + (ch ^ (row & 7))) * 8);
}

// ---------------- K1: rowsum(A), d = rsqrt, A -> bf16 ----------------
__global__ __launch_bounds__(256) void k_rowsum_scale(
    const float* __restrict__ A, float* __restrict__ rowsumA,
    float* __restrict__ dvec, unsigned short* __restrict__ Ah) {
  int row = blockIdx.x;
  int tid = threadIdx.x;
  const float4* Arow = (const float4*)(A + (size_t)row * NN);
  float s = 0.f;
#pragma unroll
  for (int l = 0; l < 4; ++l) {
    int idx = tid + l * 256;
    float4 v = Arow[idx];
    s += (v.x + v.y) + (v.z + v.w);
    ushort4 h = {f2bf(v.x), f2bf(v.y), f2bf(v.z), f2bf(v.w)};
    *(ushort4*)(Ah + (size_t)row * NN + idx * 4) = h;
  }
  __shared__ float red[256];
  red[tid] = s;
  __syncthreads();
  if (tid < 64) {
    s = red[tid] + red[tid + 64] + red[tid + 128] + red[tid + 192];
#pragma unroll
    for (int off = 32; off > 0; off >>= 1) s += __shfl_down(s, off, 64);
    if (tid == 0) { rowsumA[row] = s; dvec[row] = rsqrtf(s); }
  }
}

// ---- K2: fused  U = (scale .* x) @ W ; emit U fp32 (opt) + UTh bf16 transposed ----
__global__ __launch_bounds__(256) void k_xwt(
    const float* __restrict__ x, const float* __restrict__ scale,
    const float* __restrict__ W, float* __restrict__ U,
    unsigned short* __restrict__ UTh) {
  int r0 = blockIdx.x * 16, tid = threadIdx.x;
  int tr = tid >> 4, tc = tid & 15;
  __shared__ float Xs[16 * 132];
  __shared__ float Ws[32 * 128];
  __shared__ unsigned short Ts[128 * 16];
  __shared__ float ssc[16];
  if (tid < 16) ssc[tid] = scale[r0 + tid];
  __syncthreads();
#pragma unroll
  for (int l = 0; l < 2; ++l) {
    int idx = tid + l * 256;
    int r = idx >> 5, c4 = (idx & 31) << 2;
    float4 xv = *(const float4*)(x + (size_t)(r0 + r) * DD + c4);
    float sc = ssc[r];
    float4 o = {sc * xv.x, sc * xv.y, sc * xv.z, sc * xv.w};
    *(float4*)(Xs + r * 132 + c4) = o;
  }
  float acc[8];
#pragma unroll
  for (int u = 0; u < 8; ++u) acc[u] = 0.f;
  for (int t0 = 0; t0 < 128; t0 += 32) {
    __syncthreads();
#pragma unroll
    for (int l = 0; l < 4; ++l) {
      int idx = tid + l * 256;
      int tt = idx >> 5, c4 = (idx & 31) << 2;
      *(float4*)(Ws + tt * 128 + c4) = *(const float4*)(W + (size_t)(t0 + tt) * DD + c4);
    }
    __syncthreads();
#pragma unroll 8
    for (int tt = 0; tt < 32; ++tt) {
      float g = Xs[tr * 132 + t0 + tt];
      float4 w0 = *(const float4*)(Ws + tt * 128 + tc * 8);
      float4 w1 = *(const float4*)(Ws + tt * 128 + tc * 8 + 4);
      acc[0] = fmaf(g, w0.x, acc[0]); acc[1] = fmaf(g, w0.y, acc[1]);
      acc[2] = fmaf(g, w0.z, acc[2]); acc[3] = fmaf(g, w0.w, acc[3]);
      acc[4] = fmaf(g, w1.x, acc[4]); acc[5] = fmaf(g, w1.y, acc[5]);
      acc[6] = fmaf(g, w1.z, acc[6]); acc[7] = fmaf(g, w1.w, acc[7]);
    }
  }
  if (U) {
    size_t off = (size_t)(r0 + tr) * DD + tc * 8;
    float4 o0 = {acc[0], acc[1], acc[2], acc[3]};
    float4 o1 = {acc[4], acc[5], acc[6], acc[7]};
    *(float4*)(U + off) = o0;
    *(float4*)(U + off + 4) = o1;
  }
#pragma unroll
  for (int j = 0; j < 8; ++j) Ts[(tc * 8 + j) * 16 + tr] = f2bf(acc[j]);
  __syncthreads();
  {
    int row = tid >> 1, h = tid & 1;
    *(short8*)(UTh + (size_t)row * NN + r0 + h * 8) = *(const short8*)(Ts + row * 16 + h * 8);
  }
}

// ---- K2b: fused merge(pkey,u64 exact) -> S/d2 + U2 = (d2 .* x) @ W2 ----
__global__ __launch_bounds__(256) void k_mxwt(
    const u64* __restrict__ pkey, const float* __restrict__ rowsumA,
    const float* __restrict__ x, const float* __restrict__ W,
    float* __restrict__ sval, int* __restrict__ sidx, float* __restrict__ d2vec,
    float* __restrict__ U, unsigned short* __restrict__ UTh,
    const void* kptr, const void* sigptr) {
  int r0 = blockIdx.x * 16, tid = threadIdx.x;
  int tr = tid >> 4, tc = tid & 15;
  __shared__ float Xs[16 * 132];
  __shared__ float Ws[32 * 128];
  __shared__ unsigned short Ts[128 * 16];
  __shared__ u64 mk[256][4];
  __shared__ float ds[16];

  // parallel 16-way merge: thread (r,p) owns one partial sorted list
  {
    int r = tid >> 4, p = tid & 15;
    const u64* src = pkey + ((size_t)(r0 + r) * 16 + p) * 4;
    ulonglong2 k0 = *(const ulonglong2*)src;
    ulonglong2 k1 = *(const ulonglong2*)(src + 2);
    mk[tid][0] = k0.x; mk[tid][1] = k0.y; mk[tid][2] = k1.x; mk[tid][3] = k1.y;
  }
  __syncthreads();
#pragma unroll
  for (int s = 8; s > 0; s >>= 1) {
    int p = tid & 15;
    if (p < s) {
      u64 b[4] = {mk[tid][0], mk[tid][1], mk[tid][2], mk[tid][3]};
#pragma unroll
      for (int q = 0; q < 4; ++q) ins4(b, mk[tid + s][q]);
      mk[tid][0] = b[0]; mk[tid][1] = b[1]; mk[tid][2] = b[2]; mk[tid][3] = b[3];
    }
    __syncthreads();
  }
  if ((tid & 15) == 0) {
    int rl = tid >> 4;
    int r = r0 + rl;
    int kk = dec_i(kptr); kk = kk < 1 ? 1 : (kk > 4 ? 4 : kk);
    float inv2s = 0.5f / dec_f(sigptr);
    float srw = 0.f;
#pragma unroll
    for (int s = 0; s < 4; ++s) {
      if (s < kk) {
        u64 key = mk[tid][s];
        float d2 = __uint_as_float((unsigned)(key >> 32));
        float S = __expf(-sqrtf(d2 + 1e-10f) * inv2s);
        sval[r * 8 + s] = S;
        sidx[r * 8 + s] = (int)(key & 0xffffffffu);
        srw += S;
      }
    }
    float dd = rsqrtf(rowsumA[r] + srw);
    d2vec[r] = dd;
    ds[rl] = dd;
  }
  __syncthreads();

#pragma unroll
  for (int l = 0; l < 2; ++l) {
    int idx = tid + l * 256;
    int r = idx >> 5, c4 = (idx & 31) << 2;
    float4 xv = *(const float4*)(x + (size_t)(r0 + r) * DD + c4);
    float sc = ds[r];
    float4 o = {sc * xv.x, sc * xv.y, sc * xv.z, sc * xv.w};
    *(float4*)(Xs + r * 132 + c4) = o;
  }
  float acc[8];
#pragma unroll
  for (int u = 0; u < 8; ++u) acc[u] = 0.f;
  for (int t0 = 0; t0 < 128; t0 += 32) {
    __syncthreads();
#pragma unroll
    for (int l = 0; l < 4; ++l) {
      int idx = tid + l * 256;
      int tt = idx >> 5, c4 = (idx & 31) << 2;
      *(float4*)(Ws + tt * 128 + c4) = *(const float4*)(W + (size_t)(t0 + tt) * DD + c4);
    }
    __syncthreads();
#pragma unroll 8
    for (int tt = 0; tt < 32; ++tt) {
      float g = Xs[tr * 132 + t0 + tt];
      float4 w0 = *(const float4*)(Ws + tt * 128 + tc * 8);
      float4 w1 = *(const float4*)(Ws + tt * 128 + tc * 8 + 4);
      acc[0] = fmaf(g, w0.x, acc[0]); acc[1] = fmaf(g, w0.y, acc[1]);
      acc[2] = fmaf(g, w0.z, acc[2]); acc[3] = fmaf(g, w0.w, acc[3]);
      acc[4] = fmaf(g, w1.x, acc[4]); acc[5] = fmaf(g, w1.y, acc[5]);
      acc[6] = fmaf(g, w1.z, acc[6]); acc[7] = fmaf(g, w1.w, acc[7]);
    }
  }
  {
    size_t off = (size_t)(r0 + tr) * DD + tc * 8;
    float4 o0 = {acc[0], acc[1], acc[2], acc[3]};
    float4 o1 = {acc[4], acc[5], acc[6], acc[7]};
    *(float4*)(U + off) = o0;
    *(float4*)(U + off + 4) = o1;
  }
#pragma unroll
  for (int j = 0; j < 8; ++j) Ts[(tc * 8 + j) * 16 + tr] = f2bf(acc[j]);
  __syncthreads();
  {
    int row = tid >> 1, h = tid & 1;
    *(short8*)(UTh + (size_t)row * NN + r0 + h * 8) = *(const short8*)(Ts + row * 16 + h * 8);
  }
}

// ---- K4: MFMA bf16 GEMM, double-buffered LDS (stage next overlaps compute cur) ----
// One __syncthreads per k-step: its implicit vmcnt(0) drain waits for the DMA
// issued one iteration earlier (covered by the MFMA block in between).
template <int SPLIT>
__global__ __launch_bounds__(256) void k_gemm_bf16(
    const unsigned short* __restrict__ Ah, const unsigned short* __restrict__ Bh,
    float* __restrict__ G) {
  __shared__ __align__(16) unsigned short As_h[2][128 * 64];
  __shared__ __align__(16) unsigned short Bs_h[2][128 * 64];

  int bx = blockIdx.x;
  int mt = bx / SPLIT, sp = bx % SPLIT;
  int m0 = mt * 128;
  const int KLEN = NN / SPLIT;
  int ks = sp * KLEN;
  int tid = threadIdx.x, lane = tid & 63, w = tid >> 6;
  int wm = w >> 1, wn = w & 1;
  int l15 = lane & 15, quad = lane >> 4;

  f32x4 acc[4][4];
#pragma unroll
  for (int a = 0; a < 4; ++a)
#pragma unroll
    for (int b = 0; b < 4; ++b) acc[a][b] = (f32x4){0.f, 0.f, 0.f, 0.f};

  // prologue: stage first tile into buffer 0
  stage2<128, 64, 256>(Ah, m0, ks, As_h[0], tid, NN);
  stage2<128, 64, 256>(Bh, 0, ks, Bs_h[0], tid, NN);

  for (int kt = 0; kt < KLEN; kt += 64) {
    int cur = (kt >> 6) & 1;
    __syncthreads();   // drains vmcnt: buf[cur] DMA complete; prev reads of buf[cur^1] done
    if (kt + 64 < KLEN) {
      stage2<128, 64, 256>(Ah, m0, ks + kt + 64, As_h[cur ^ 1], tid, NN);
      stage2<128, 64, 256>(Bh, 0, ks + kt + 64, Bs_h[cur ^ 1], tid, NN);
    }
#pragma unroll
    for (int k0 = 0; k0 < 64; k0 += 32) {
      int ch = (k0 >> 3) + quad;
      short8 a_h[4], b_h[4];
#pragma unroll
      for (int f = 0; f < 4; ++f) {
        a_h[f] = fragN<8>(As_h[cur], wm * 64 + f * 16 + l15, ch);
        b_h[f] = fragN<8>(Bs_h[cur], wn * 64 + f * 16 + l15, ch);
      }
#pragma unroll
      for (int fm = 0; fm < 4; ++fm)
#pragma unroll
        for (int fn = 0; fn < 4; ++fn)
          acc[fm][fn] = __builtin_amdgcn_mfma_f32_16x16x32_bf16(a_h[fm], b_h[fn], acc[fm][fn], 0, 0, 0);
    }
  }
  float* Gp = G + (size_t)sp * NN * DD;
#pragma unroll
  for (int fm = 0; fm < 4; ++fm) {
    int rb = m0 + wm * 64 + fm * 16 + quad * 4;
#pragma unroll
    for (int fn = 0; fn < 4; ++fn) {
      int c = wn * 64 + fn * 16 + l15;
#pragma unroll
      for (int i = 0; i < 4; ++i)
        Gp[(size_t)(rb + i) * DD + c] = acc[fm][fn][i];
    }
  }
}

// ---- K5: Out/Z = act( d * (sum_p G_p [+ sparse]) + b ); optional zh/sq emission ----
template <int NP>
__global__ __launch_bounds__(256) void k_red(
    const float* __restrict__ G, const float* __restrict__ dvec,
    const float* __restrict__ bvec, int leaky,
    float* __restrict__ Out, unsigned short* __restrict__ zh,
    float* __restrict__ sqout,
    const float* __restrict__ Usp, const float* __restrict__ sval,
    const int* __restrict__ sidx, const void* kptr) {
  int r0 = blockIdx.x * 16;
  int tid = threadIdx.x;
  int tr = tid >> 4, tc = tid & 15;
  int r = r0 + tr;
  size_t off = (size_t)r * DD + tc * 8;
  __shared__ float red[256];

  float acc[8];
#pragma unroll
  for (int u = 0; u < 8; ++u) acc[u] = 0.f;
#pragma unroll
  for (int p = 0; p < NP; ++p) {
    const float* gp = G + (size_t)p * NN * DD + off;
    float4 g0 = *(const float4*)gp;
    float4 g1 = *(const float4*)(gp + 4);
    acc[0] += g0.x; acc[1] += g0.y; acc[2] += g0.z; acc[3] += g0.w;
    acc[4] += g1.x; acc[5] += g1.y; acc[6] += g1.z; acc[7] += g1.w;
  }
  if (sidx != nullptr) {
    int kk = dec_i(kptr); kk = kk < 1 ? 1 : (kk > 4 ? 4 : kk);
    for (int t = 0; t < kk; ++t) {
      float sv = sval[r * 8 + t];
      int id = sidx[r * 8 + t];
      const float* vr = Usp + (size_t)id * DD + tc * 8;
      float4 w0 = *(const float4*)vr;
      float4 w1 = *(const float4*)(vr + 4);
      acc[0] = fmaf(sv, w0.x, acc[0]); acc[1] = fmaf(sv, w0.y, acc[1]);
      acc[2] = fmaf(sv, w0.z, acc[2]); acc[3] = fmaf(sv, w0.w, acc[3]);
      acc[4] = fmaf(sv, w1.x, acc[4]); acc[5] = fmaf(sv, w1.y, acc[5]);
      acc[6] = fmaf(sv, w1.z, acc[6]); acc[7] = fmaf(sv, w1.w, acc[7]);
    }
  }
  float d = dvec[r];
  float4 b0 = *(const float4*)(bvec + tc * 8);
  float4 b1 = *(const float4*)(bvec + tc * 8 + 4);
  float bb[8] = {b0.x, b0.y, b0.z, b0.w, b1.x, b1.y, b1.z, b1.w};
  float o[8];
#pragma unroll
  for (int u = 0; u < 8; ++u) {
    float v = fmaf(d, acc[u], bb[u]);
    if (leaky) v = v > 0.f ? v : 0.1f * v;
    o[u] = v;
  }
  if (Out) {
    float4 o0 = {o[0], o[1], o[2], o[3]};
    float4 o1 = {o[4], o[5], o[6], o[7]};
    *(float4*)(Out + off) = o0;
    *(float4*)(Out + off + 4) = o1;
  }
  if (zh) {
    ushort4 h0 = {f2bf(o[0]), f2bf(o[1]), f2bf(o[2]), f2bf(o[3])};
    ushort4 h1 = {f2bf(o[4]), f2bf(o[5]), f2bf(o[6]), f2bf(o[7])};
    *(ushort4*)(zh + off) = h0;
    *(ushort4*)(zh + off + 4) = h1;
  }
  if (sqout != nullptr) {
    float p = 0.f;
#pragma unroll
    for (int u = 0; u < 8; ++u) p = fmaf(o[u], o[u], p);
    red[tid] = p;
    __syncthreads();
    if (tc == 0) {
      float s = 0.f;
#pragma unroll
      for (int i = 0; i < 16; ++i) s += red[tr * 16 + i];
      sqout[r] = s;
    }
  }
}

// ---- K6: MFMA bf16 Z@Z^T, fused d2-key top-4 per (row, j-slice), u64 exact keys ----
// grid 1024: mt (64 m-tiles of 64) x jp (16 j-slices of 256); block 512 (8 waves)
__global__ __launch_bounds__(512, 8) void k_scores(
    const unsigned short* __restrict__ Zh,
    const float* __restrict__ sq, u64* __restrict__ pkey) {
  __shared__ __align__(16) unsigned short Am[64 * 128];   // 16 KB; merge lists alias
  __shared__ __align__(16) unsigned short Bj[64 * 128];   // 16 KB; Stile aliases
  float* Stile = (float*)&Bj[0];          // [64][64], XOR-swizzled float4 slots
  u64* mv = (u64*)&Am[0];                 // [512][4] packed keys (16 KB)

  int bx = blockIdx.x;
  int mt = bx >> 4, jp = bx & 15;
  int m0 = mt * 64, j0 = jp * 256;
  int tid = threadIdx.x, lane = tid & 63, w = tid >> 6;
  int wm = w >> 2, wn = w & 3;            // wave tile: 32 rows x 16 cols
  int l15 = lane & 15, quad = lane >> 4;

  stage2<64, 128, 512>(Zh, m0, 0, Am, tid, DD);

  int srow = tid >> 3;         // scan row 0..63
  int sc = tid & 7;            // scan col-octet
  float sqi_r = sq[m0 + srow];

  u64 lst[4];
#pragma unroll
  for (int s = 0; s < 4; ++s) lst[s] = ~0ull;
  unsigned cutb = 0xffffffffu;            // hi32 of lst[3]

  for (int jt = 0; jt < 4; ++jt) {
    int jrow0 = j0 + jt * 64;
    __syncthreads();           // prev scan done (Stile = Bj about to be restaged)
    stage2<64, 128, 512>(Zh, jrow0, 0, Bj, tid, DD);
    __syncthreads();           // DMA visible (covers A on first iter)

    f32x4 acc[2];
    acc[0] = (f32x4){0.f, 0.f, 0.f, 0.f};
    acc[1] = (f32x4){0.f, 0.f, 0.f, 0.f};
#pragma unroll
    for (int kc = 0; kc < 4; ++kc) {
      int ch = kc * 4 + quad;
      short8 ah0 = fragN<16>(Am, wm * 32 + l15, ch);
      short8 ah1 = fragN<16>(Am, wm * 32 + 16 + l15, ch);
      short8 bh  = fragN<16>(Bj, wn * 16 + l15, ch);
      acc[0] = __builtin_amdgcn_mfma_f32_16x16x32_bf16(ah0, bh, acc[0], 0, 0, 0);
      acc[1] = __builtin_amdgcn_mfma_f32_16x16x32_bf16(ah1, bh, acc[1], 0, 0, 0);
    }
    __syncthreads();           // all Bj/Am frag reads done before Stile clobbers Bj

    // epilogue: Stile[r][c] = sqj - 2*dot, swizzled slot = (c>>2)^(r&7)
    {
      int c = wn * 16 + l15;
      float sqjv = sq[jrow0 + c];
      int cslot = c >> 2, cw = c & 3;
#pragma unroll
      for (int fm = 0; fm < 2; ++fm) {
        int rb = wm * 32 + fm * 16 + quad * 4;
#pragma unroll
        for (int i = 0; i < 4; ++i) {
          int r = rb + i;
          Stile[r * 64 + ((cslot ^ (r & 7)) << 2) + cw] = fmaf(-2.f, acc[fm][i], sqjv);
        }
      }
    }
    __syncthreads();           // Stile visible

    // scan: 8 threads/row, 8 cands each (2 swizzled float4 reads)
    // exact early-exit: packed key > lst[3] is a no-op insert; v>=0 so bit
    // order = float order -> skip iff float_bits(v) > hi32(lst[3]).
#pragma unroll
    for (int q = 0; q < 2; ++q) {
      int slot = sc * 2 + q;
      float4 kv = *(const float4*)(Stile + srow * 64 + ((slot ^ (srow & 7)) << 2));
      int jb = jrow0 + sc * 8 + q * 4;
      float ke[4] = {kv.x, kv.y, kv.z, kv.w};
#pragma unroll
      for (int e = 0; e < 4; ++e) {
        float v = fmaxf(sqi_r + ke[e], 0.f);
        unsigned vb = __float_as_uint(v);
        if (vb <= cutb) {
          ins4(lst, ((u64)vb << 32) | (unsigned)(jb + e));
          cutb = (unsigned)(lst[3] >> 32);
        }
      }
    }
  }

  __syncthreads();             // last scan + last Am frag reads done
#pragma unroll
  for (int s = 0; s < 4; ++s) mv[tid * 4 + s] = lst[s];
  __syncthreads();
  if (tid < 64) {
    u64 best[4] = {~0ull, ~0ull, ~0ull, ~0ull};
    for (int g = 0; g < 8; ++g) {
      int src = tid * 8 + g;
#pragma unroll
      for (int s = 0; s < 4; ++s) ins4(best, mv[src * 4 + s]);
    }
#pragma unroll
    for (int s = 0; s < 4; ++s)
      pkey[((size_t)(m0 + tid) * 16 + jp) * 4 + s] = best[s];
  }
}

extern "C" void kernel_launch(void* const* d_in, const int* in_sizes, int n_in,
                              void* d_out, int out_size, void* d_ws, size_t ws_size,
                              hipStream_t stream) {
  const float* x  = (const float*)d_in[0];
  const float* A  = (const float*)d_in[1];
  const float* W1 = (const float*)d_in[2];
  const float* b1 = (const float*)d_in[3];
  const float* W2 = (const float*)d_in[4];
  const float* b2 = (const float*)d_in[5];
  const void* sig = (n_in > 6) ? d_in[6] : nullptr;
  const void* kp  = (n_in > 7) ? d_in[7] : nullptr;

  float* ws = (float*)d_ws;
  float* rowsumA = ws;                                   // 4096
  float* dvec    = ws + 4096;                            // 4096
  float* d2vec   = ws + 8192;                            // 4096
  float* sqv     = ws + 12288;                           // 4096
  float* sval    = ws + 16384;                           // 32768
  int*   sidx    = (int*)(ws + 49152);                   // 32768
  u64*   pkey    = (u64*)(ws + 81920);                   // 262144 u64 = 524288 floats
  unsigned short* Zh  = (unsigned short*)(ws + 606208);  // 524288 u16 = 262144 floats
  float* U       = ws + 868352;                          // 524288 f32
  unsigned short* UTh = (unsigned short*)(ws + 1392640); // 524288 u16 = 262144 floats
  unsigned short* Ah  = (unsigned short*)(ws + 1654784); // 16777216 u16 = 8388608 floats
  float* G       = ws + 10043392;                        // SPLIT * 524288 f32

  const size_t F16 = 10043392 + 16 * 524288;  // ~73.7 MB in floats
  int split16 = (ws_size >= F16 * 4);

  k_rowsum_scale<<<4096, 256, 0, stream>>>(A, rowsumA, dvec, Ah);
  // pass 1: Z = leaky(d * (A @ ((d.*x)@W1)) + b1), emit Zh + sq
  k_xwt<<<256, 256, 0, stream>>>(x, dvec, W1, nullptr, UTh);
  if (split16) {
    k_gemm_bf16<16><<<512, 256, 0, stream>>>(Ah, UTh, G);
    k_red<16><<<256, 256, 0, stream>>>(G, dvec, b1, 1, nullptr, Zh, sqv,
                                       nullptr, nullptr, nullptr, nullptr);
  } else {
    k_gemm_bf16<4><<<128, 256, 0, stream>>>(Ah, UTh, G);
    k_red<4><<<256, 256, 0, stream>>>(G, dvec, b1, 1, nullptr, Zh, sqv,
                                      nullptr, nullptr, nullptr, nullptr);
  }
  // scores + top-k
  k_scores<<<1024, 512, 0, stream>>>(Zh, sqv, pkey);
  // fused merge + pass-2 feature transform
  k_mxwt<<<256, 256, 0, stream>>>(pkey, rowsumA, x, W2, sval, sidx, d2vec,
                                  U, UTh, kp, sig);
  // pass 2: out = d2 * (A @ ((d2.*x)@W2) + sparse) + b2
  if (split16) {
    k_gemm_bf16<16><<<512, 256, 0, stream>>>(Ah, UTh, G);
    k_red<16><<<256, 256, 0, stream>>>(G, d2vec, b2, 0, (float*)d_out, nullptr, nullptr,
                                       U, sval, sidx, kp);
  } else {
    k_gemm_bf16<4><<<128, 256, 0, stream>>>(Ah, UTh, G);
    k_red<4><<<256, 256, 0, stream>>>(G, d2vec, b2, 0, (float*)d_out, nullptr, nullptr,
                                      U, sval, sidx, kp);
  }
}

// Round 5
// 204.952 us; speedup vs baseline: 2.0680x; 1.0115x over previous
//
#include <hip/hip_runtime.h>
#include <cstdint>
#include <cstddef>

#define NN 4096
#define DD 128

using short8 = __attribute__((ext_vector_type(8))) short;
using f32x4  = __attribute__((ext_vector_type(4))) float;
typedef unsigned long long u64;

typedef __attribute__((address_space(1))) void gvoid;
typedef __attribute__((address_space(3))) void lvoid;

__device__ __forceinline__ void async16(const void* g, void* l) {
  __builtin_amdgcn_global_load_lds((gvoid*)g, (lvoid*)l, 16, 0, 0);
}

__device__ __forceinline__ float dec_f(const void* p) {
  if (!p) return 1.0f;
  int b = *(const int*)p;
  return (b >= 0 && b < 1000000) ? (float)b : __int_as_float(b);
}
__device__ __forceinline__ int dec_i(const void* p) {
  if (!p) return 4;
  int b = *(const int*)p;
  return (b >= 0 && b < 1000000) ? b : (int)__int_as_float(b);
}

__device__ __forceinline__ unsigned short f2bf(float f) {
  union { float f; unsigned int u; } v; v.f = f;
  unsigned int u = v.u;
  unsigned int r = (u + 0x7fffu + ((u >> 16) & 1u)) >> 16;
  return (unsigned short)r;
}

// sorted-4 insert of packed key (d2_bits<<32 | idx), ascending (exact)
__device__ __forceinline__ void ins4(u64 (&l)[4], u64 k) {
#pragma unroll
  for (int t = 0; t < 4; ++t) {
    u64 old = l[t];
    bool bt = k < old;
    l[t] = bt ? k : old;
    k = bt ? old : k;
  }
}

// stage ROWS x KC bf16 tile (16B chunks; physical chunk p holds logical p^(r&7))
template <int ROWS, int KC, int NTHR>
__device__ __forceinline__ void stage2(const unsigned short* src, int row0, int kb,
                                       unsigned short* dst, int tid, int stride) {
  const int CPR = KC / 8;
  const int ITER = (ROWS * CPR) / NTHR;
#pragma unroll
  for (int t = 0; t < ITER; ++t) {
    int id = tid + t * NTHR;
    int r = id / CPR;
    int p = id % CPR;
    int lc = p ^ (r & 7);
    const void* g = src + (size_t)(row0 + r) * stride + kb + lc * 8;
    async16(g, dst + (size_t)(id & ~63) * 8);
  }
}

template <int CPR>
__device__ __forceinline__ short8 fragN(const unsigned short* t, int row, int ch) {
  return *(const short8*)(t + (size_t)(row * CPR + (ch ^ (row & 7))) * 8);
}

// ---------------- K1: rowsum(A), d = rsqrt, A -> bf16 ----------------
__global__ __launch_bounds__(256) void k_rowsum_scale(
    const float* __restrict__ A, float* __restrict__ rowsumA,
    float* __restrict__ dvec, unsigned short* __restrict__ Ah) {
  int row = blockIdx.x;
  int tid = threadIdx.x;
  const float4* Arow = (const float4*)(A + (size_t)row * NN);
  float s = 0.f;
#pragma unroll
  for (int l = 0; l < 4; ++l) {
    int idx = tid + l * 256;
    float4 v = Arow[idx];
    s += (v.x + v.y) + (v.z + v.w);
    ushort4 h = {f2bf(v.x), f2bf(v.y), f2bf(v.z), f2bf(v.w)};
    *(ushort4*)(Ah + (size_t)row * NN + idx * 4) = h;
  }
  __shared__ float red[256];
  red[tid] = s;
  __syncthreads();
  if (tid < 64) {
    s = red[tid] + red[tid + 64] + red[tid + 128] + red[tid + 192];
#pragma unroll
    for (int off = 32; off > 0; off >>= 1) s += __shfl_down(s, off, 64);
    if (tid == 0) { rowsumA[row] = s; dvec[row] = rsqrtf(s); }
  }
}

// ---- K2: fused  U = (scale .* x) @ W ; emit U fp32 (opt) + UTh bf16 transposed ----
__global__ __launch_bounds__(256) void k_xwt(
    const float* __restrict__ x, const float* __restrict__ scale,
    const float* __restrict__ W, float* __restrict__ U,
    unsigned short* __restrict__ UTh) {
  int r0 = blockIdx.x * 16, tid = threadIdx.x;
  int tr = tid >> 4, tc = tid & 15;
  __shared__ float Xs[16 * 132];
  __shared__ float Ws[32 * 128];
  __shared__ unsigned short Ts[128 * 16];
  __shared__ float ssc[16];
  if (tid < 16) ssc[tid] = scale[r0 + tid];
  __syncthreads();
#pragma unroll
  for (int l = 0; l < 2; ++l) {
    int idx = tid + l * 256;
    int r = idx >> 5, c4 = (idx & 31) << 2;
    float4 xv = *(const float4*)(x + (size_t)(r0 + r) * DD + c4);
    float sc = ssc[r];
    float4 o = {sc * xv.x, sc * xv.y, sc * xv.z, sc * xv.w};
    *(float4*)(Xs + r * 132 + c4) = o;
  }
  float acc[8];
#pragma unroll
  for (int u = 0; u < 8; ++u) acc[u] = 0.f;
  for (int t0 = 0; t0 < 128; t0 += 32) {
    __syncthreads();
#pragma unroll
    for (int l = 0; l < 4; ++l) {
      int idx = tid + l * 256;
      int tt = idx >> 5, c4 = (idx & 31) << 2;
      *(float4*)(Ws + tt * 128 + c4) = *(const float4*)(W + (size_t)(t0 + tt) * DD + c4);
    }
    __syncthreads();
#pragma unroll 8
    for (int tt = 0; tt < 32; ++tt) {
      float g = Xs[tr * 132 + t0 + tt];
      float4 w0 = *(const float4*)(Ws + tt * 128 + tc * 8);
      float4 w1 = *(const float4*)(Ws + tt * 128 + tc * 8 + 4);
      acc[0] = fmaf(g, w0.x, acc[0]); acc[1] = fmaf(g, w0.y, acc[1]);
      acc[2] = fmaf(g, w0.z, acc[2]); acc[3] = fmaf(g, w0.w, acc[3]);
      acc[4] = fmaf(g, w1.x, acc[4]); acc[5] = fmaf(g, w1.y, acc[5]);
      acc[6] = fmaf(g, w1.z, acc[6]); acc[7] = fmaf(g, w1.w, acc[7]);
    }
  }
  if (U) {
    size_t off = (size_t)(r0 + tr) * DD + tc * 8;
    float4 o0 = {acc[0], acc[1], acc[2], acc[3]};
    float4 o1 = {acc[4], acc[5], acc[6], acc[7]};
    *(float4*)(U + off) = o0;
    *(float4*)(U + off + 4) = o1;
  }
#pragma unroll
  for (int j = 0; j < 8; ++j) Ts[(tc * 8 + j) * 16 + tr] = f2bf(acc[j]);
  __syncthreads();
  {
    int row = tid >> 1, h = tid & 1;
    *(short8*)(UTh + (size_t)row * NN + r0 + h * 8) = *(const short8*)(Ts + row * 16 + h * 8);
  }
}

// ---- K2b: fused merge(pkey,u64 exact) -> S/d2 + U2 = (d2 .* x) @ W2 ----
__global__ __launch_bounds__(256) void k_mxwt(
    const u64* __restrict__ pkey, const float* __restrict__ rowsumA,
    const float* __restrict__ x, const float* __restrict__ W,
    float* __restrict__ sval, int* __restrict__ sidx, float* __restrict__ d2vec,
    float* __restrict__ U, unsigned short* __restrict__ UTh,
    const void* kptr, const void* sigptr) {
  int r0 = blockIdx.x * 16, tid = threadIdx.x;
  int tr = tid >> 4, tc = tid & 15;
  __shared__ float Xs[16 * 132];
  __shared__ float Ws[32 * 128];
  __shared__ unsigned short Ts[128 * 16];
  __shared__ u64 mk[256][4];
  __shared__ float ds[16];

  // parallel 16-way merge: thread (r,p) owns one partial sorted list
  {
    int r = tid >> 4, p = tid & 15;
    const u64* src = pkey + ((size_t)(r0 + r) * 16 + p) * 4;
    ulonglong2 k0 = *(const ulonglong2*)src;
    ulonglong2 k1 = *(const ulonglong2*)(src + 2);
    mk[tid][0] = k0.x; mk[tid][1] = k0.y; mk[tid][2] = k1.x; mk[tid][3] = k1.y;
  }
  __syncthreads();
#pragma unroll
  for (int s = 8; s > 0; s >>= 1) {
    int p = tid & 15;
    if (p < s) {
      u64 b[4] = {mk[tid][0], mk[tid][1], mk[tid][2], mk[tid][3]};
#pragma unroll
      for (int q = 0; q < 4; ++q) ins4(b, mk[tid + s][q]);
      mk[tid][0] = b[0]; mk[tid][1] = b[1]; mk[tid][2] = b[2]; mk[tid][3] = b[3];
    }
    __syncthreads();
  }
  if ((tid & 15) == 0) {
    int rl = tid >> 4;
    int r = r0 + rl;
    int kk = dec_i(kptr); kk = kk < 1 ? 1 : (kk > 4 ? 4 : kk);
    float inv2s = 0.5f / dec_f(sigptr);
    float srw = 0.f;
#pragma unroll
    for (int s = 0; s < 4; ++s) {
      if (s < kk) {
        u64 key = mk[tid][s];
        float d2 = __uint_as_float((unsigned)(key >> 32));
        float S = __expf(-sqrtf(d2 + 1e-10f) * inv2s);
        sval[r * 8 + s] = S;
        sidx[r * 8 + s] = (int)(key & 0xffffffffu);
        srw += S;
      }
    }
    float dd = rsqrtf(rowsumA[r] + srw);
    d2vec[r] = dd;
    ds[rl] = dd;
  }
  __syncthreads();

#pragma unroll
  for (int l = 0; l < 2; ++l) {
    int idx = tid + l * 256;
    int r = idx >> 5, c4 = (idx & 31) << 2;
    float4 xv = *(const float4*)(x + (size_t)(r0 + r) * DD + c4);
    float sc = ds[r];
    float4 o = {sc * xv.x, sc * xv.y, sc * xv.z, sc * xv.w};
    *(float4*)(Xs + r * 132 + c4) = o;
  }
  float acc[8];
#pragma unroll
  for (int u = 0; u < 8; ++u) acc[u] = 0.f;
  for (int t0 = 0; t0 < 128; t0 += 32) {
    __syncthreads();
#pragma unroll
    for (int l = 0; l < 4; ++l) {
      int idx = tid + l * 256;
      int tt = idx >> 5, c4 = (idx & 31) << 2;
      *(float4*)(Ws + tt * 128 + c4) = *(const float4*)(W + (size_t)(t0 + tt) * DD + c4);
    }
    __syncthreads();
#pragma unroll 8
    for (int tt = 0; tt < 32; ++tt) {
      float g = Xs[tr * 132 + t0 + tt];
      float4 w0 = *(const float4*)(Ws + tt * 128 + tc * 8);
      float4 w1 = *(const float4*)(Ws + tt * 128 + tc * 8 + 4);
      acc[0] = fmaf(g, w0.x, acc[0]); acc[1] = fmaf(g, w0.y, acc[1]);
      acc[2] = fmaf(g, w0.z, acc[2]); acc[3] = fmaf(g, w0.w, acc[3]);
      acc[4] = fmaf(g, w1.x, acc[4]); acc[5] = fmaf(g, w1.y, acc[5]);
      acc[6] = fmaf(g, w1.z, acc[6]); acc[7] = fmaf(g, w1.w, acc[7]);
    }
  }
  {
    size_t off = (size_t)(r0 + tr) * DD + tc * 8;
    float4 o0 = {acc[0], acc[1], acc[2], acc[3]};
    float4 o1 = {acc[4], acc[5], acc[6], acc[7]};
    *(float4*)(U + off) = o0;
    *(float4*)(U + off + 4) = o1;
  }
#pragma unroll
  for (int j = 0; j < 8; ++j) Ts[(tc * 8 + j) * 16 + tr] = f2bf(acc[j]);
  __syncthreads();
  {
    int row = tid >> 1, h = tid & 1;
    *(short8*)(UTh + (size_t)row * NN + r0 + h * 8) = *(const short8*)(Ts + row * 16 + h * 8);
  }
}

// ---- K4: MFMA bf16 GEMM, 64-row m-tiles x SPLIT -> 4 blocks/CU for latency hiding ----
// Single-buffered 2-barrier loop (known-good). Per-output-element MFMA K-order
// identical to the 128-row version -> G bit-identical.
template <int SPLIT>
__global__ __launch_bounds__(256) void k_gemm_bf16(
    const unsigned short* __restrict__ Ah, const unsigned short* __restrict__ Bh,
    float* __restrict__ G) {
  __shared__ __align__(16) unsigned short As_h[64 * 64];    // 8 KB
  __shared__ __align__(16) unsigned short Bs_h[128 * 64];   // 16 KB

  int bx = blockIdx.x;
  int mt = bx / SPLIT, sp = bx % SPLIT;
  int m0 = mt * 64;
  const int KLEN = NN / SPLIT;
  int ks = sp * KLEN;
  int tid = threadIdx.x, lane = tid & 63, w = tid >> 6;
  int wm = w >> 1, wn = w & 1;          // wave tile: 32 rows x 64 cols
  int l15 = lane & 15, quad = lane >> 4;

  f32x4 acc[2][4];
#pragma unroll
  for (int a = 0; a < 2; ++a)
#pragma unroll
    for (int b = 0; b < 4; ++b) acc[a][b] = (f32x4){0.f, 0.f, 0.f, 0.f};

  for (int kt = 0; kt < KLEN; kt += 64) {
    int kb = ks + kt;
    __syncthreads();
    stage2<64, 64, 256>(Ah, m0, kb, As_h, tid, NN);
    stage2<128, 64, 256>(Bh, 0, kb, Bs_h, tid, NN);
    __syncthreads();
#pragma unroll
    for (int k0 = 0; k0 < 64; k0 += 32) {
      int ch = (k0 >> 3) + quad;
      short8 a_h[2], b_h[4];
#pragma unroll
      for (int f = 0; f < 2; ++f)
        a_h[f] = fragN<8>(As_h, wm * 32 + f * 16 + l15, ch);
#pragma unroll
      for (int f = 0; f < 4; ++f)
        b_h[f] = fragN<8>(Bs_h, wn * 64 + f * 16 + l15, ch);
#pragma unroll
      for (int fm = 0; fm < 2; ++fm)
#pragma unroll
        for (int fn = 0; fn < 4; ++fn)
          acc[fm][fn] = __builtin_amdgcn_mfma_f32_16x16x32_bf16(a_h[fm], b_h[fn], acc[fm][fn], 0, 0, 0);
    }
  }
  float* Gp = G + (size_t)sp * NN * DD;
#pragma unroll
  for (int fm = 0; fm < 2; ++fm) {
    int rb = m0 + wm * 32 + fm * 16 + quad * 4;
#pragma unroll
    for (int fn = 0; fn < 4; ++fn) {
      int c = wn * 64 + fn * 16 + l15;
#pragma unroll
      for (int i = 0; i < 4; ++i)
        Gp[(size_t)(rb + i) * DD + c] = acc[fm][fn][i];
    }
  }
}

// ---- K5: Out/Z = act( d * (sum_p G_p [+ sparse]) + b ); optional zh/sq emission ----
template <int NP>
__global__ __launch_bounds__(256) void k_red(
    const float* __restrict__ G, const float* __restrict__ dvec,
    const float* __restrict__ bvec, int leaky,
    float* __restrict__ Out, unsigned short* __restrict__ zh,
    float* __restrict__ sqout,
    const float* __restrict__ Usp, const float* __restrict__ sval,
    const int* __restrict__ sidx, const void* kptr) {
  int r0 = blockIdx.x * 16;
  int tid = threadIdx.x;
  int tr = tid >> 4, tc = tid & 15;
  int r = r0 + tr;
  size_t off = (size_t)r * DD + tc * 8;
  __shared__ float red[256];

  float acc[8];
#pragma unroll
  for (int u = 0; u < 8; ++u) acc[u] = 0.f;
#pragma unroll
  for (int p = 0; p < NP; ++p) {
    const float* gp = G + (size_t)p * NN * DD + off;
    float4 g0 = *(const float4*)gp;
    float4 g1 = *(const float4*)(gp + 4);
    acc[0] += g0.x; acc[1] += g0.y; acc[2] += g0.z; acc[3] += g0.w;
    acc[4] += g1.x; acc[5] += g1.y; acc[6] += g1.z; acc[7] += g1.w;
  }
  if (sidx != nullptr) {
    int kk = dec_i(kptr); kk = kk < 1 ? 1 : (kk > 4 ? 4 : kk);
    for (int t = 0; t < kk; ++t) {
      float sv = sval[r * 8 + t];
      int id = sidx[r * 8 + t];
      const float* vr = Usp + (size_t)id * DD + tc * 8;
      float4 w0 = *(const float4*)vr;
      float4 w1 = *(const float4*)(vr + 4);
      acc[0] = fmaf(sv, w0.x, acc[0]); acc[1] = fmaf(sv, w0.y, acc[1]);
      acc[2] = fmaf(sv, w0.z, acc[2]); acc[3] = fmaf(sv, w0.w, acc[3]);
      acc[4] = fmaf(sv, w1.x, acc[4]); acc[5] = fmaf(sv, w1.y, acc[5]);
      acc[6] = fmaf(sv, w1.z, acc[6]); acc[7] = fmaf(sv, w1.w, acc[7]);
    }
  }
  float d = dvec[r];
  float4 b0 = *(const float4*)(bvec + tc * 8);
  float4 b1 = *(const float4*)(bvec + tc * 8 + 4);
  float bb[8] = {b0.x, b0.y, b0.z, b0.w, b1.x, b1.y, b1.z, b1.w};
  float o[8];
#pragma unroll
  for (int u = 0; u < 8; ++u) {
    float v = fmaf(d, acc[u], bb[u]);
    if (leaky) v = v > 0.f ? v : 0.1f * v;
    o[u] = v;
  }
  if (Out) {
    float4 o0 = {o[0], o[1], o[2], o[3]};
    float4 o1 = {o[4], o[5], o[6], o[7]};
    *(float4*)(Out + off) = o0;
    *(float4*)(Out + off + 4) = o1;
  }
  if (zh) {
    ushort4 h0 = {f2bf(o[0]), f2bf(o[1]), f2bf(o[2]), f2bf(o[3])};
    ushort4 h1 = {f2bf(o[4]), f2bf(o[5]), f2bf(o[6]), f2bf(o[7])};
    *(ushort4*)(zh + off) = h0;
    *(ushort4*)(zh + off + 4) = h1;
  }
  if (sqout != nullptr) {
    float p = 0.f;
#pragma unroll
    for (int u = 0; u < 8; ++u) p = fmaf(o[u], o[u], p);
    red[tid] = p;
    __syncthreads();
    if (tc == 0) {
      float s = 0.f;
#pragma unroll
      for (int i = 0; i < 16; ++i) s += red[tr * 16 + i];
      sqout[r] = s;
    }
  }
}

// ---- K6: MFMA bf16 Z@Z^T, fused d2-key top-4 per (row, j-slice), u64 exact keys ----
// grid 1024: mt (64 m-tiles of 64) x jp (16 j-slices of 256); block 512 (8 waves)
__global__ __launch_bounds__(512, 8) void k_scores(
    const unsigned short* __restrict__ Zh,
    const float* __restrict__ sq, u64* __restrict__ pkey) {
  __shared__ __align__(16) unsigned short Am[64 * 128];   // 16 KB; merge lists alias
  __shared__ __align__(16) unsigned short Bj[64 * 128];   // 16 KB; Stile aliases
  float* Stile = (float*)&Bj[0];          // [64][64], XOR-swizzled float4 slots
  u64* mv = (u64*)&Am[0];                 // [512][4] packed keys (16 KB)

  int bx = blockIdx.x;
  int mt = bx >> 4, jp = bx & 15;
  int m0 = mt * 64, j0 = jp * 256;
  int tid = threadIdx.x, lane = tid & 63, w = tid >> 6;
  int wm = w >> 2, wn = w & 3;            // wave tile: 32 rows x 16 cols
  int l15 = lane & 15, quad = lane >> 4;

  stage2<64, 128, 512>(Zh, m0, 0, Am, tid, DD);

  int srow = tid >> 3;         // scan row 0..63
  int sc = tid & 7;            // scan col-octet
  float sqi_r = sq[m0 + srow];

  u64 lst[4];
#pragma unroll
  for (int s = 0; s < 4; ++s) lst[s] = ~0ull;
  unsigned cutb = 0xffffffffu;            // hi32 of lst[3]

  for (int jt = 0; jt < 4; ++jt) {
    int jrow0 = j0 + jt * 64;
    __syncthreads();           // prev scan done (Stile = Bj about to be restaged)
    stage2<64, 128, 512>(Zh, jrow0, 0, Bj, tid, DD);
    __syncthreads();           // DMA visible (covers A on first iter)

    f32x4 acc[2];
    acc[0] = (f32x4){0.f, 0.f, 0.f, 0.f};
    acc[1] = (f32x4){0.f, 0.f, 0.f, 0.f};
#pragma unroll
    for (int kc = 0; kc < 4; ++kc) {
      int ch = kc * 4 + quad;
      short8 ah0 = fragN<16>(Am, wm * 32 + l15, ch);
      short8 ah1 = fragN<16>(Am, wm * 32 + 16 + l15, ch);
      short8 bh  = fragN<16>(Bj, wn * 16 + l15, ch);
      acc[0] = __builtin_amdgcn_mfma_f32_16x16x32_bf16(ah0, bh, acc[0], 0, 0, 0);
      acc[1] = __builtin_amdgcn_mfma_f32_16x16x32_bf16(ah1, bh, acc[1], 0, 0, 0);
    }
    __syncthreads();           // all Bj/Am frag reads done before Stile clobbers Bj

    // epilogue: Stile[r][c] = sqj - 2*dot, swizzled slot = (c>>2)^(r&7)
    {
      int c = wn * 16 + l15;
      float sqjv = sq[jrow0 + c];
      int cslot = c >> 2, cw = c & 3;
#pragma unroll
      for (int fm = 0; fm < 2; ++fm) {
        int rb = wm * 32 + fm * 16 + quad * 4;
#pragma unroll
        for (int i = 0; i < 4; ++i) {
          int r = rb + i;
          Stile[r * 64 + ((cslot ^ (r & 7)) << 2) + cw] = fmaf(-2.f, acc[fm][i], sqjv);
        }
      }
    }
    __syncthreads();           // Stile visible

    // scan: 8 threads/row, 8 cands each (2 swizzled float4 reads)
    // exact early-exit: packed key > lst[3] is a no-op insert; v>=0 so bit
    // order = float order -> skip iff float_bits(v) > hi32(lst[3]).
#pragma unroll
    for (int q = 0; q < 2; ++q) {
      int slot = sc * 2 + q;
      float4 kv = *(const float4*)(Stile + srow * 64 + ((slot ^ (srow & 7)) << 2));
      int jb = jrow0 + sc * 8 + q * 4;
      float ke[4] = {kv.x, kv.y, kv.z, kv.w};
#pragma unroll
      for (int e = 0; e < 4; ++e) {
        float v = fmaxf(sqi_r + ke[e], 0.f);
        unsigned vb = __float_as_uint(v);
        if (vb <= cutb) {
          ins4(lst, ((u64)vb << 32) | (unsigned)(jb + e));
          cutb = (unsigned)(lst[3] >> 32);
        }
      }
    }
  }

  __syncthreads();             // last scan + last Am frag reads done
#pragma unroll
  for (int s = 0; s < 4; ++s) mv[tid * 4 + s] = lst[s];
  __syncthreads();
  if (tid < 64) {
    u64 best[4] = {~0ull, ~0ull, ~0ull, ~0ull};
    for (int g = 0; g < 8; ++g) {
      int src = tid * 8 + g;
#pragma unroll
      for (int s = 0; s < 4; ++s) ins4(best, mv[src * 4 + s]);
    }
#pragma unroll
    for (int s = 0; s < 4; ++s)
      pkey[((size_t)(m0 + tid) * 16 + jp) * 4 + s] = best[s];
  }
}

extern "C" void kernel_launch(void* const* d_in, const int* in_sizes, int n_in,
                              void* d_out, int out_size, void* d_ws, size_t ws_size,
                              hipStream_t stream) {
  const float* x  = (const float*)d_in[0];
  const float* A  = (const float*)d_in[1];
  const float* W1 = (const float*)d_in[2];
  const float* b1 = (const float*)d_in[3];
  const float* W2 = (const float*)d_in[4];
  const float* b2 = (const float*)d_in[5];
  const void* sig = (n_in > 6) ? d_in[6] : nullptr;
  const void* kp  = (n_in > 7) ? d_in[7] : nullptr;

  float* ws = (float*)d_ws;
  float* rowsumA = ws;                                   // 4096
  float* dvec    = ws + 4096;                            // 4096
  float* d2vec   = ws + 8192;                            // 4096
  float* sqv     = ws + 12288;                           // 4096
  float* sval    = ws + 16384;                           // 32768
  int*   sidx    = (int*)(ws + 49152);                   // 32768
  u64*   pkey    = (u64*)(ws + 81920);                   // 262144 u64 = 524288 floats
  unsigned short* Zh  = (unsigned short*)(ws + 606208);  // 524288 u16 = 262144 floats
  float* U       = ws + 868352;                          // 524288 f32
  unsigned short* UTh = (unsigned short*)(ws + 1392640); // 524288 u16 = 262144 floats
  unsigned short* Ah  = (unsigned short*)(ws + 1654784); // 16777216 u16 = 8388608 floats
  float* G       = ws + 10043392;                        // SPLIT * 524288 f32

  const size_t F16 = 10043392 + 16 * 524288;  // ~73.7 MB in floats
  int split16 = (ws_size >= F16 * 4);

  k_rowsum_scale<<<4096, 256, 0, stream>>>(A, rowsumA, dvec, Ah);
  // pass 1: Z = leaky(d * (A @ ((d.*x)@W1)) + b1), emit Zh + sq
  k_xwt<<<256, 256, 0, stream>>>(x, dvec, W1, nullptr, UTh);
  if (split16) {
    k_gemm_bf16<16><<<1024, 256, 0, stream>>>(Ah, UTh, G);
    k_red<16><<<256, 256, 0, stream>>>(G, dvec, b1, 1, nullptr, Zh, sqv,
                                       nullptr, nullptr, nullptr, nullptr);
  } else {
    k_gemm_bf16<4><<<256, 256, 0, stream>>>(Ah, UTh, G);
    k_red<4><<<256, 256, 0, stream>>>(G, dvec, b1, 1, nullptr, Zh, sqv,
                                      nullptr, nullptr, nullptr, nullptr);
  }
  // scores + top-k
  k_scores<<<1024, 512, 0, stream>>>(Zh, sqv, pkey);
  // fused merge + pass-2 feature transform
  k_mxwt<<<256, 256, 0, stream>>>(pkey, rowsumA, x, W2, sval, sidx, d2vec,
                                  U, UTh, kp, sig);
  // pass 2: out = d2 * (A @ ((d2.*x)@W2) + sparse) + b2
  if (split16) {
    k_gemm_bf16<16><<<1024, 256, 0, stream>>>(Ah, UTh, G);
    k_red<16><<<256, 256, 0, stream>>>(G, d2vec, b2, 0, (float*)d_out, nullptr, nullptr,
                                       U, sval, sidx, kp);
  } else {
    k_gemm_bf16<4><<<256, 256, 0, stream>>>(Ah, UTh, G);
    k_red<4><<<256, 256, 0, stream>>>(G, d2vec, b2, 0, (float*)d_out, nullptr, nullptr,
                                      U, sval, sidx, kp);
  }
}

// Round 6
// 196.572 us; speedup vs baseline: 2.1562x; 1.0426x over previous
//
#include <hip/hip_runtime.h>
#include <cstdint>
#include <cstddef>

#define NN 4096
#define DD 128

using short8 = __attribute__((ext_vector_type(8))) short;
using f32x4  = __attribute__((ext_vector_type(4))) float;
typedef unsigned long long u64;

typedef __attribute__((address_space(1))) void gvoid;
typedef __attribute__((address_space(3))) void lvoid;

__device__ __forceinline__ void async16(const void* g, void* l) {
  __builtin_amdgcn_global_load_lds((gvoid*)g, (lvoid*)l, 16, 0, 0);
}

__device__ __forceinline__ float dec_f(const void* p) {
  if (!p) return 1.0f;
  int b = *(const int*)p;
  return (b >= 0 && b < 1000000) ? (float)b : __int_as_float(b);
}
__device__ __forceinline__ int dec_i(const void* p) {
  if (!p) return 4;
  int b = *(const int*)p;
  return (b >= 0 && b < 1000000) ? b : (int)__int_as_float(b);
}

__device__ __forceinline__ unsigned short f2bf(float f) {
  union { float f; unsigned int u; } v; v.f = f;
  unsigned int u = v.u;
  unsigned int r = (u + 0x7fffu + ((u >> 16) & 1u)) >> 16;
  return (unsigned short)r;
}

// sorted-4 insert of packed key (d2_bits<<32 | idx), ascending (exact)
__device__ __forceinline__ void ins4(u64 (&l)[4], u64 k) {
#pragma unroll
  for (int t = 0; t < 4; ++t) {
    u64 old = l[t];
    bool bt = k < old;
    l[t] = bt ? k : old;
    k = bt ? old : k;
  }
}

// stage ROWS x KC bf16 tile (16B chunks; physical chunk p holds logical p^(r&7))
template <int ROWS, int KC, int NTHR>
__device__ __forceinline__ void stage2(const unsigned short* src, int row0, int kb,
                                       unsigned short* dst, int tid, int stride) {
  const int CPR = KC / 8;
  const int ITER = (ROWS * CPR) / NTHR;
#pragma unroll
  for (int t = 0; t < ITER; ++t) {
    int id = tid + t * NTHR;
    int r = id / CPR;
    int p = id % CPR;
    int lc = p ^ (r & 7);
    const void* g = src + (size_t)(row0 + r) * stride + kb + lc * 8;
    async16(g, dst + (size_t)(id & ~63) * 8);
  }
}

template <int CPR>
__device__ __forceinline__ short8 fragN(const unsigned short* t, int row, int ch) {
  return *(const short8*)(t + (size_t)(row * CPR + (ch ^ (row & 7))) * 8);
}

// ---------------- K1: rowsum(A), d = rsqrt, A -> bf16 ----------------
__global__ __launch_bounds__(256) void k_rowsum_scale(
    const float* __restrict__ A, float* __restrict__ rowsumA,
    float* __restrict__ dvec, unsigned short* __restrict__ Ah) {
  int row = blockIdx.x;
  int tid = threadIdx.x;
  const float4* Arow = (const float4*)(A + (size_t)row * NN);
  float s = 0.f;
#pragma unroll
  for (int l = 0; l < 4; ++l) {
    int idx = tid + l * 256;
    float4 v = Arow[idx];
    s += (v.x + v.y) + (v.z + v.w);
    ushort4 h = {f2bf(v.x), f2bf(v.y), f2bf(v.z), f2bf(v.w)};
    *(ushort4*)(Ah + (size_t)row * NN + idx * 4) = h;
  }
  __shared__ float red[256];
  red[tid] = s;
  __syncthreads();
  if (tid < 64) {
    s = red[tid] + red[tid + 64] + red[tid + 128] + red[tid + 192];
#pragma unroll
    for (int off = 32; off > 0; off >>= 1) s += __shfl_down(s, off, 64);
    if (tid == 0) { rowsumA[row] = s; dvec[row] = rsqrtf(s); }
  }
}

// ---- K2: fused  U = (scale .* x) @ W ; emit U fp32 (opt) + UTh bf16 transposed ----
__global__ __launch_bounds__(256) void k_xwt(
    const float* __restrict__ x, const float* __restrict__ scale,
    const float* __restrict__ W, float* __restrict__ U,
    unsigned short* __restrict__ UTh) {
  int r0 = blockIdx.x * 16, tid = threadIdx.x;
  int tr = tid >> 4, tc = tid & 15;
  __shared__ float Xs[16 * 132];
  __shared__ float Ws[32 * 128];
  __shared__ unsigned short Ts[128 * 16];
  __shared__ float ssc[16];
  if (tid < 16) ssc[tid] = scale[r0 + tid];
  __syncthreads();
#pragma unroll
  for (int l = 0; l < 2; ++l) {
    int idx = tid + l * 256;
    int r = idx >> 5, c4 = (idx & 31) << 2;
    float4 xv = *(const float4*)(x + (size_t)(r0 + r) * DD + c4);
    float sc = ssc[r];
    float4 o = {sc * xv.x, sc * xv.y, sc * xv.z, sc * xv.w};
    *(float4*)(Xs + r * 132 + c4) = o;
  }
  float acc[8];
#pragma unroll
  for (int u = 0; u < 8; ++u) acc[u] = 0.f;
  for (int t0 = 0; t0 < 128; t0 += 32) {
    __syncthreads();
#pragma unroll
    for (int l = 0; l < 4; ++l) {
      int idx = tid + l * 256;
      int tt = idx >> 5, c4 = (idx & 31) << 2;
      *(float4*)(Ws + tt * 128 + c4) = *(const float4*)(W + (size_t)(t0 + tt) * DD + c4);
    }
    __syncthreads();
#pragma unroll 8
    for (int tt = 0; tt < 32; ++tt) {
      float g = Xs[tr * 132 + t0 + tt];
      float4 w0 = *(const float4*)(Ws + tt * 128 + tc * 8);
      float4 w1 = *(const float4*)(Ws + tt * 128 + tc * 8 + 4);
      acc[0] = fmaf(g, w0.x, acc[0]); acc[1] = fmaf(g, w0.y, acc[1]);
      acc[2] = fmaf(g, w0.z, acc[2]); acc[3] = fmaf(g, w0.w, acc[3]);
      acc[4] = fmaf(g, w1.x, acc[4]); acc[5] = fmaf(g, w1.y, acc[5]);
      acc[6] = fmaf(g, w1.z, acc[6]); acc[7] = fmaf(g, w1.w, acc[7]);
    }
  }
  if (U) {
    size_t off = (size_t)(r0 + tr) * DD + tc * 8;
    float4 o0 = {acc[0], acc[1], acc[2], acc[3]};
    float4 o1 = {acc[4], acc[5], acc[6], acc[7]};
    *(float4*)(U + off) = o0;
    *(float4*)(U + off + 4) = o1;
  }
#pragma unroll
  for (int j = 0; j < 8; ++j) Ts[(tc * 8 + j) * 16 + tr] = f2bf(acc[j]);
  __syncthreads();
  {
    int row = tid >> 1, h = tid & 1;
    *(short8*)(UTh + (size_t)row * NN + r0 + h * 8) = *(const short8*)(Ts + row * 16 + h * 8);
  }
}

// ---- K2b: fused merge(pkey,u64 exact) -> S/d2 + U2 = (d2 .* x) @ W2 ----
__global__ __launch_bounds__(256) void k_mxwt(
    const u64* __restrict__ pkey, const float* __restrict__ rowsumA,
    const float* __restrict__ x, const float* __restrict__ W,
    float* __restrict__ sval, int* __restrict__ sidx, float* __restrict__ d2vec,
    float* __restrict__ U, unsigned short* __restrict__ UTh,
    const void* kptr, const void* sigptr) {
  int r0 = blockIdx.x * 16, tid = threadIdx.x;
  int tr = tid >> 4, tc = tid & 15;
  __shared__ float Xs[16 * 132];
  __shared__ float Ws[32 * 128];
  __shared__ unsigned short Ts[128 * 16];
  __shared__ u64 mk[256][4];
  __shared__ float ds[16];

  // parallel 16-way merge: thread (r,p) owns one partial sorted list
  {
    int r = tid >> 4, p = tid & 15;
    const u64* src = pkey + ((size_t)(r0 + r) * 16 + p) * 4;
    ulonglong2 k0 = *(const ulonglong2*)src;
    ulonglong2 k1 = *(const ulonglong2*)(src + 2);
    mk[tid][0] = k0.x; mk[tid][1] = k0.y; mk[tid][2] = k1.x; mk[tid][3] = k1.y;
  }
  __syncthreads();
#pragma unroll
  for (int s = 8; s > 0; s >>= 1) {
    int p = tid & 15;
    if (p < s) {
      u64 b[4] = {mk[tid][0], mk[tid][1], mk[tid][2], mk[tid][3]};
#pragma unroll
      for (int q = 0; q < 4; ++q) ins4(b, mk[tid + s][q]);
      mk[tid][0] = b[0]; mk[tid][1] = b[1]; mk[tid][2] = b[2]; mk[tid][3] = b[3];
    }
    __syncthreads();
  }
  if ((tid & 15) == 0) {
    int rl = tid >> 4;
    int r = r0 + rl;
    int kk = dec_i(kptr); kk = kk < 1 ? 1 : (kk > 4 ? 4 : kk);
    float inv2s = 0.5f / dec_f(sigptr);
    float srw = 0.f;
#pragma unroll
    for (int s = 0; s < 4; ++s) {
      if (s < kk) {
        u64 key = mk[tid][s];
        float d2 = __uint_as_float((unsigned)(key >> 32));
        float S = __expf(-sqrtf(d2 + 1e-10f) * inv2s);
        sval[r * 8 + s] = S;
        sidx[r * 8 + s] = (int)(key & 0xffffffffu);
        srw += S;
      }
    }
    float dd = rsqrtf(rowsumA[r] + srw);
    d2vec[r] = dd;
    ds[rl] = dd;
  }
  __syncthreads();

#pragma unroll
  for (int l = 0; l < 2; ++l) {
    int idx = tid + l * 256;
    int r = idx >> 5, c4 = (idx & 31) << 2;
    float4 xv = *(const float4*)(x + (size_t)(r0 + r) * DD + c4);
    float sc = ds[r];
    float4 o = {sc * xv.x, sc * xv.y, sc * xv.z, sc * xv.w};
    *(float4*)(Xs + r * 132 + c4) = o;
  }
  float acc[8];
#pragma unroll
  for (int u = 0; u < 8; ++u) acc[u] = 0.f;
  for (int t0 = 0; t0 < 128; t0 += 32) {
    __syncthreads();
#pragma unroll
    for (int l = 0; l < 4; ++l) {
      int idx = tid + l * 256;
      int tt = idx >> 5, c4 = (idx & 31) << 2;
      *(float4*)(Ws + tt * 128 + c4) = *(const float4*)(W + (size_t)(t0 + tt) * DD + c4);
    }
    __syncthreads();
#pragma unroll 8
    for (int tt = 0; tt < 32; ++tt) {
      float g = Xs[tr * 132 + t0 + tt];
      float4 w0 = *(const float4*)(Ws + tt * 128 + tc * 8);
      float4 w1 = *(const float4*)(Ws + tt * 128 + tc * 8 + 4);
      acc[0] = fmaf(g, w0.x, acc[0]); acc[1] = fmaf(g, w0.y, acc[1]);
      acc[2] = fmaf(g, w0.z, acc[2]); acc[3] = fmaf(g, w0.w, acc[3]);
      acc[4] = fmaf(g, w1.x, acc[4]); acc[5] = fmaf(g, w1.y, acc[5]);
      acc[6] = fmaf(g, w1.z, acc[6]); acc[7] = fmaf(g, w1.w, acc[7]);
    }
  }
  {
    size_t off = (size_t)(r0 + tr) * DD + tc * 8;
    float4 o0 = {acc[0], acc[1], acc[2], acc[3]};
    float4 o1 = {acc[4], acc[5], acc[6], acc[7]};
    *(float4*)(U + off) = o0;
    *(float4*)(U + off + 4) = o1;
  }
#pragma unroll
  for (int j = 0; j < 8; ++j) Ts[(tc * 8 + j) * 16 + tr] = f2bf(acc[j]);
  __syncthreads();
  {
    int row = tid >> 1, h = tid & 1;
    *(short8*)(UTh + (size_t)row * NN + r0 + h * 8) = *(const short8*)(Ts + row * 16 + h * 8);
  }
}

// ---- K4: MFMA bf16 GEMM, 128x128 m-tile, 512 threads (8 waves) for latency hiding ----
// Same staging bytes/layout as the 256-thread version; per-output MFMA K-chain
// identical (each output's chain lives in one wave, same order) -> G bit-identical.
template <int SPLIT>
__global__ __launch_bounds__(512) void k_gemm_bf16(
    const unsigned short* __restrict__ Ah, const unsigned short* __restrict__ Bh,
    float* __restrict__ G) {
  __shared__ __align__(16) unsigned short As_h[128 * 64];
  __shared__ __align__(16) unsigned short Bs_h[128 * 64];

  int bx = blockIdx.x;
  int mt = bx / SPLIT, sp = bx % SPLIT;
  int m0 = mt * 128;
  const int KLEN = NN / SPLIT;
  int ks = sp * KLEN;
  int tid = threadIdx.x, lane = tid & 63, w = tid >> 6;   // 8 waves
  int wm = w >> 1, wn = w & 1;          // wave tile: 32 rows x 64 cols
  int l15 = lane & 15, quad = lane >> 4;

  f32x4 acc[2][4];
#pragma unroll
  for (int a = 0; a < 2; ++a)
#pragma unroll
    for (int b = 0; b < 4; ++b) acc[a][b] = (f32x4){0.f, 0.f, 0.f, 0.f};

  for (int kt = 0; kt < KLEN; kt += 64) {
    int kb = ks + kt;
    __syncthreads();
    stage2<128, 64, 512>(Ah, m0, kb, As_h, tid, NN);
    stage2<128, 64, 512>(Bh, 0, kb, Bs_h, tid, NN);
    __syncthreads();
#pragma unroll
    for (int k0 = 0; k0 < 64; k0 += 32) {
      int ch = (k0 >> 3) + quad;
      short8 a_h[2], b_h[4];
#pragma unroll
      for (int f = 0; f < 2; ++f)
        a_h[f] = fragN<8>(As_h, wm * 32 + f * 16 + l15, ch);
#pragma unroll
      for (int f = 0; f < 4; ++f)
        b_h[f] = fragN<8>(Bs_h, wn * 64 + f * 16 + l15, ch);
#pragma unroll
      for (int fm = 0; fm < 2; ++fm)
#pragma unroll
        for (int fn = 0; fn < 4; ++fn)
          acc[fm][fn] = __builtin_amdgcn_mfma_f32_16x16x32_bf16(a_h[fm], b_h[fn], acc[fm][fn], 0, 0, 0);
    }
  }
  float* Gp = G + (size_t)sp * NN * DD;
#pragma unroll
  for (int fm = 0; fm < 2; ++fm) {
    int rb = m0 + wm * 32 + fm * 16 + quad * 4;
#pragma unroll
    for (int fn = 0; fn < 4; ++fn) {
      int c = wn * 64 + fn * 16 + l15;
#pragma unroll
      for (int i = 0; i < 4; ++i)
        Gp[(size_t)(rb + i) * DD + c] = acc[fm][fn][i];
    }
  }
}

// ---- K5: Out/Z = act( d * (sum_p G_p [+ sparse]) + b ); optional zh/sq emission ----
template <int NP>
__global__ __launch_bounds__(256) void k_red(
    const float* __restrict__ G, const float* __restrict__ dvec,
    const float* __restrict__ bvec, int leaky,
    float* __restrict__ Out, unsigned short* __restrict__ zh,
    float* __restrict__ sqout,
    const float* __restrict__ Usp, const float* __restrict__ sval,
    const int* __restrict__ sidx, const void* kptr) {
  int r0 = blockIdx.x * 16;
  int tid = threadIdx.x;
  int tr = tid >> 4, tc = tid & 15;
  int r = r0 + tr;
  size_t off = (size_t)r * DD + tc * 8;
  __shared__ float red[256];

  float acc[8];
#pragma unroll
  for (int u = 0; u < 8; ++u) acc[u] = 0.f;
#pragma unroll
  for (int p = 0; p < NP; ++p) {
    const float* gp = G + (size_t)p * NN * DD + off;
    float4 g0 = *(const float4*)gp;
    float4 g1 = *(const float4*)(gp + 4);
    acc[0] += g0.x; acc[1] += g0.y; acc[2] += g0.z; acc[3] += g0.w;
    acc[4] += g1.x; acc[5] += g1.y; acc[6] += g1.z; acc[7] += g1.w;
  }
  if (sidx != nullptr) {
    int kk = dec_i(kptr); kk = kk < 1 ? 1 : (kk > 4 ? 4 : kk);
    for (int t = 0; t < kk; ++t) {
      float sv = sval[r * 8 + t];
      int id = sidx[r * 8 + t];
      const float* vr = Usp + (size_t)id * DD + tc * 8;
      float4 w0 = *(const float4*)vr;
      float4 w1 = *(const float4*)(vr + 4);
      acc[0] = fmaf(sv, w0.x, acc[0]); acc[1] = fmaf(sv, w0.y, acc[1]);
      acc[2] = fmaf(sv, w0.z, acc[2]); acc[3] = fmaf(sv, w0.w, acc[3]);
      acc[4] = fmaf(sv, w1.x, acc[4]); acc[5] = fmaf(sv, w1.y, acc[5]);
      acc[6] = fmaf(sv, w1.z, acc[6]); acc[7] = fmaf(sv, w1.w, acc[7]);
    }
  }
  float d = dvec[r];
  float4 b0 = *(const float4*)(bvec + tc * 8);
  float4 b1 = *(const float4*)(bvec + tc * 8 + 4);
  float bb[8] = {b0.x, b0.y, b0.z, b0.w, b1.x, b1.y, b1.z, b1.w};
  float o[8];
#pragma unroll
  for (int u = 0; u < 8; ++u) {
    float v = fmaf(d, acc[u], bb[u]);
    if (leaky) v = v > 0.f ? v : 0.1f * v;
    o[u] = v;
  }
  if (Out) {
    float4 o0 = {o[0], o[1], o[2], o[3]};
    float4 o1 = {o[4], o[5], o[6], o[7]};
    *(float4*)(Out + off) = o0;
    *(float4*)(Out + off + 4) = o1;
  }
  if (zh) {
    ushort4 h0 = {f2bf(o[0]), f2bf(o[1]), f2bf(o[2]), f2bf(o[3])};
    ushort4 h1 = {f2bf(o[4]), f2bf(o[5]), f2bf(o[6]), f2bf(o[7])};
    *(ushort4*)(zh + off) = h0;
    *(ushort4*)(zh + off + 4) = h1;
  }
  if (sqout != nullptr) {
    float p = 0.f;
#pragma unroll
    for (int u = 0; u < 8; ++u) p = fmaf(o[u], o[u], p);
    red[tid] = p;
    __syncthreads();
    if (tc == 0) {
      float s = 0.f;
#pragma unroll
      for (int i = 0; i < 16; ++i) s += red[tr * 16 + i];
      sqout[r] = s;
    }
  }
}

// ---- K6: MFMA bf16 Z@Z^T, fused d2-key top-4 per (row, j-slice), u64 exact keys ----
// grid 1024: mt (64 m-tiles of 64) x jp (16 j-slices of 256); block 512 (8 waves)
__global__ __launch_bounds__(512, 8) void k_scores(
    const unsigned short* __restrict__ Zh,
    const float* __restrict__ sq, u64* __restrict__ pkey) {
  __shared__ __align__(16) unsigned short Am[64 * 128];   // 16 KB; merge lists alias
  __shared__ __align__(16) unsigned short Bj[64 * 128];   // 16 KB; Stile aliases
  float* Stile = (float*)&Bj[0];          // [64][64], XOR-swizzled float4 slots
  u64* mv = (u64*)&Am[0];                 // [512][4] packed keys (16 KB)

  int bx = blockIdx.x;
  int mt = bx >> 4, jp = bx & 15;
  int m0 = mt * 64, j0 = jp * 256;
  int tid = threadIdx.x, lane = tid & 63, w = tid >> 6;
  int wm = w >> 2, wn = w & 3;            // wave tile: 32 rows x 16 cols
  int l15 = lane & 15, quad = lane >> 4;

  stage2<64, 128, 512>(Zh, m0, 0, Am, tid, DD);

  int srow = tid >> 3;         // scan row 0..63
  int sc = tid & 7;            // scan col-octet
  float sqi_r = sq[m0 + srow];

  u64 lst[4];
#pragma unroll
  for (int s = 0; s < 4; ++s) lst[s] = ~0ull;

  for (int jt = 0; jt < 4; ++jt) {
    int jrow0 = j0 + jt * 64;
    __syncthreads();           // prev scan done (Stile = Bj about to be restaged)
    stage2<64, 128, 512>(Zh, jrow0, 0, Bj, tid, DD);
    __syncthreads();           // DMA visible (covers A on first iter)

    f32x4 acc[2];
    acc[0] = (f32x4){0.f, 0.f, 0.f, 0.f};
    acc[1] = (f32x4){0.f, 0.f, 0.f, 0.f};
#pragma unroll
    for (int kc = 0; kc < 4; ++kc) {
      int ch = kc * 4 + quad;
      short8 ah0 = fragN<16>(Am, wm * 32 + l15, ch);
      short8 ah1 = fragN<16>(Am, wm * 32 + 16 + l15, ch);
      short8 bh  = fragN<16>(Bj, wn * 16 + l15, ch);
      acc[0] = __builtin_amdgcn_mfma_f32_16x16x32_bf16(ah0, bh, acc[0], 0, 0, 0);
      acc[1] = __builtin_amdgcn_mfma_f32_16x16x32_bf16(ah1, bh, acc[1], 0, 0, 0);
    }
    __syncthreads();           // all Bj/Am frag reads done before Stile clobbers Bj

    // epilogue: Stile[r][c] = sqj - 2*dot, swizzled slot = (c>>2)^(r&7)
    {
      int c = wn * 16 + l15;
      float sqjv = sq[jrow0 + c];
      int cslot = c >> 2, cw = c & 3;
#pragma unroll
      for (int fm = 0; fm < 2; ++fm) {
        int rb = wm * 32 + fm * 16 + quad * 4;
#pragma unroll
        for (int i = 0; i < 4; ++i) {
          int r = rb + i;
          Stile[r * 64 + ((cslot ^ (r & 7)) << 2) + cw] = fmaf(-2.f, acc[fm][i], sqjv);
        }
      }
    }
    __syncthreads();           // Stile visible

    // scan: 8 threads/row, 8 cands each (2 swizzled float4 reads)
#pragma unroll
    for (int q = 0; q < 2; ++q) {
      int slot = sc * 2 + q;
      float4 kv = *(const float4*)(Stile + srow * 64 + ((slot ^ (srow & 7)) << 2));
      int jb = jrow0 + sc * 8 + q * 4;
      float ke[4] = {kv.x, kv.y, kv.z, kv.w};
#pragma unroll
      for (int e = 0; e < 4; ++e) {
        float v = fmaxf(sqi_r + ke[e], 0.f);
        ins4(lst, ((u64)__float_as_uint(v) << 32) | (unsigned)(jb + e));
      }
    }
  }

  __syncthreads();             // last scan + last Am frag reads done
#pragma unroll
  for (int s = 0; s < 4; ++s) mv[tid * 4 + s] = lst[s];
  __syncthreads();
  if (tid < 64) {
    u64 best[4] = {~0ull, ~0ull, ~0ull, ~0ull};
    for (int g = 0; g < 8; ++g) {
      int src = tid * 8 + g;
#pragma unroll
      for (int s = 0; s < 4; ++s) ins4(best, mv[src * 4 + s]);
    }
#pragma unroll
    for (int s = 0; s < 4; ++s)
      pkey[((size_t)(m0 + tid) * 16 + jp) * 4 + s] = best[s];
  }
}

extern "C" void kernel_launch(void* const* d_in, const int* in_sizes, int n_in,
                              void* d_out, int out_size, void* d_ws, size_t ws_size,
                              hipStream_t stream) {
  const float* x  = (const float*)d_in[0];
  const float* A  = (const float*)d_in[1];
  const float* W1 = (const float*)d_in[2];
  const float* b1 = (const float*)d_in[3];
  const float* W2 = (const float*)d_in[4];
  const float* b2 = (const float*)d_in[5];
  const void* sig = (n_in > 6) ? d_in[6] : nullptr;
  const void* kp  = (n_in > 7) ? d_in[7] : nullptr;

  float* ws = (float*)d_ws;
  float* rowsumA = ws;                                   // 4096
  float* dvec    = ws + 4096;                            // 4096
  float* d2vec   = ws + 8192;                            // 4096
  float* sqv     = ws + 12288;                           // 4096
  float* sval    = ws + 16384;                           // 32768
  int*   sidx    = (int*)(ws + 49152);                   // 32768
  u64*   pkey    = (u64*)(ws + 81920);                   // 262144 u64 = 524288 floats
  unsigned short* Zh  = (unsigned short*)(ws + 606208);  // 524288 u16 = 262144 floats
  float* U       = ws + 868352;                          // 524288 f32
  unsigned short* UTh = (unsigned short*)(ws + 1392640); // 524288 u16 = 262144 floats
  unsigned short* Ah  = (unsigned short*)(ws + 1654784); // 16777216 u16 = 8388608 floats
  float* G       = ws + 10043392;                        // SPLIT * 524288 f32

  const size_t F16 = 10043392 + 16 * 524288;  // ~73.7 MB in floats
  int split16 = (ws_size >= F16 * 4);

  k_rowsum_scale<<<4096, 256, 0, stream>>>(A, rowsumA, dvec, Ah);
  // pass 1: Z = leaky(d * (A @ ((d.*x)@W1)) + b1), emit Zh + sq
  k_xwt<<<256, 256, 0, stream>>>(x, dvec, W1, nullptr, UTh);
  if (split16) {
    k_gemm_bf16<16><<<512, 512, 0, stream>>>(Ah, UTh, G);
    k_red<16><<<256, 256, 0, stream>>>(G, dvec, b1, 1, nullptr, Zh, sqv,
                                       nullptr, nullptr, nullptr, nullptr);
  } else {
    k_gemm_bf16<4><<<128, 512, 0, stream>>>(Ah, UTh, G);
    k_red<4><<<256, 256, 0, stream>>>(G, dvec, b1, 1, nullptr, Zh, sqv,
                                      nullptr, nullptr, nullptr, nullptr);
  }
  // scores + top-k
  k_scores<<<1024, 512, 0, stream>>>(Zh, sqv, pkey);
  // fused merge + pass-2 feature transform
  k_mxwt<<<256, 256, 0, stream>>>(pkey, rowsumA, x, W2, sval, sidx, d2vec,
                                  U, UTh, kp, sig);
  // pass 2: out = d2 * (A @ ((d2.*x)@W2) + sparse) + b2
  if (split16) {
    k_gemm_bf16<16><<<512, 512, 0, stream>>>(Ah, UTh, G);
    k_red<16><<<256, 256, 0, stream>>>(G, d2vec, b2, 0, (float*)d_out, nullptr, nullptr,
                                       U, sval, sidx, kp);
  } else {
    k_gemm_bf16<4><<<128, 512, 0, stream>>>(Ah, UTh, G);
    k_red<4><<<256, 256, 0, stream>>>(G, d2vec, b2, 0, (float*)d_out, nullptr, nullptr,
                                      U, sval, sidx, kp);
  }
}